// Round 5
// baseline (4848.301 us; speedup 1.0000x reference)
//
#include <hip/hip_runtime.h>

#define NNODES 100000
#define NEDGES 3200000
#define NFEATS 128
#define HID 64
#define NGRAPHS 64
#define NPB 128                              // nodes per bucket
#define NBUCK ((NNODES + NPB - 1) / NPB)     // 782
#define NBLKA 128                            // binning blocks
#define EPB (NEDGES / NBLKA)                 // 25000 edges per binning block

// ---------- setup ----------

__global__ __launch_bounds__(256) void k_init(int* cnt, float* pooled, float* gcnt) {
    int i = blockIdx.x * 256 + threadIdx.x;
    if (i < NNODES) cnt[i] = 0;
    if (i < NGRAPHS * HID) pooled[i] = 0.f;
    if (i < NGRAPHS) gcnt[i] = 0.f;
}

__global__ __launch_bounds__(256) void k_count(const int* __restrict__ dst, int* __restrict__ cnt) {
    int e = blockIdx.x * 256 + threadIdx.x;
    if (e < NEDGES) atomicAdd(&cnt[dst[e]], 1);
}

__global__ __launch_bounds__(256) void k_dinv(const int* __restrict__ cnt, float* __restrict__ dinv) {
    int i = blockIdx.x * 256 + threadIdx.x;
    if (i < NNODES) dinv[i] = rsqrtf((float)(cnt[i] + 1));   // +1 self loop, always > 0
}

// per-block LDS histogram over buckets -> cntmat[b][j]. zero global atomics.
__global__ __launch_bounds__(256) void k_hist(const int* __restrict__ dst, int* __restrict__ cntmat) {
    __shared__ int h[NBUCK];
    for (int j = threadIdx.x; j < NBUCK; j += 256) h[j] = 0;
    __syncthreads();
    int e0 = blockIdx.x * EPB;
    for (int i = threadIdx.x; i < EPB; i += 256) atomicAdd(&h[dst[e0 + i] >> 7], 1);
    __syncthreads();
    for (int j = threadIdx.x; j < NBUCK; j += 256) cntmat[blockIdx.x * NBUCK + j] = h[j];
}

// single block: bucket totals -> exclusive bases (wave scan) -> per-(block,bucket) offsets
__global__ __launch_bounds__(256) void k_offs(const int* __restrict__ cntmat, int* __restrict__ offmat,
                                              int* __restrict__ bbase) {
    __shared__ int tot[NBUCK];
    __shared__ int bex[NBUCK];
    int tid = threadIdx.x;
    for (int j = tid; j < NBUCK; j += 256) {
        int s = 0;
        for (int b = 0; b < NBLKA; b++) s += cntmat[b * NBUCK + j];
        tot[j] = s;
    }
    __syncthreads();
    if (tid < 64) {   // wave 0: exclusive scan over 782 totals
        int run = 0;
        for (int c = 0; c < NBUCK; c += 64) {
            int j = c + tid;
            int own = (j < NBUCK) ? tot[j] : 0;
            int v = own;
            for (int off = 1; off < 64; off <<= 1) {
                int u = __shfl_up(v, off);
                if (tid >= off) v += u;
            }
            if (j < NBUCK) bex[j] = run + v - own;
            run += __shfl(v, 63);
        }
    }
    __syncthreads();
    for (int j = tid; j < NBUCK; j += 256) {
        int run = bex[j];
        bbase[j] = run;
        for (int b = 0; b < NBLKA; b++) { offmat[b * NBUCK + j] = run; run += cntmat[b * NBUCK + j]; }
    }
    if (tid == 0) bbase[NBUCK] = NEDGES;
}

// place edges: LDS cursors (no global atomics), 8B packed record (s|dloc<<17, w)
__global__ __launch_bounds__(256) void k_bin(const int* __restrict__ src, const int* __restrict__ dst,
                                             const float* __restrict__ dinv, const int* __restrict__ offmat,
                                             int2* __restrict__ ebin) {
    __shared__ int cur[NBUCK];
    int b = blockIdx.x;
    for (int j = threadIdx.x; j < NBUCK; j += 256) cur[j] = offmat[b * NBUCK + j];
    __syncthreads();
    int e0 = b * EPB;
    for (int i = threadIdx.x; i < EPB; i += 256) {
        int s = src[e0 + i], d = dst[e0 + i];
        int p = atomicAdd(&cur[d >> 7], 1);
        float w = dinv[s] * dinv[d];
        ebin[p] = make_int2(s | ((d & (NPB - 1)) << 17), __float_as_int(w));
    }
}

// ---------- transform (GEMV per node, wave-uniform W -> s_load) ----------

#define CHK 32
#define CHKP 33   // +1 pad: conflict-free stride

// block = 128 nodes x 2 col-halves (256 threads). Thread owns 32 output cols
// of one node; acc in 32 VGPRs. x staged coalesced to LDS per 32-k chunk.
// Safe when in == agg: block reads exactly the rows it writes, and every
// global read precedes the final __syncthreads().
template <int K, bool RELU>
__global__ __launch_bounds__(256) void k_mm(const float* __restrict__ in, const float* __restrict__ W,
                                            const float* __restrict__ bias, const float* __restrict__ dinv,
                                            float* __restrict__ t_out, float* __restrict__ agg) {
    __shared__ float xs[128 * CHKP];
    const int tid = threadIdx.x;
    const int lane = tid & 63;
    const int wid = tid >> 6;
    const int jhalf = __builtin_amdgcn_readfirstlane(wid & 1);
    const int nloc = (wid >> 1) * 64 + lane;   // 0..127 local node
    const int node0 = blockIdx.x * 128;
    const int node = node0 + nloc;

    float acc[32];
#pragma unroll
    for (int j = 0; j < 32; j++) acc[j] = 0.f;

    const int c4 = tid & 7;     // float4 slot in row (8 per 32-float chunk)
    const int r0 = tid >> 3;    // 0..31

    for (int ko = 0; ko < K; ko += CHK) {
        __syncthreads();
#pragma unroll
        for (int s = 0; s < 4; s++) {
            int r = r0 + s * 32;
            int gn = node0 + r;
            float4 v = make_float4(0.f, 0.f, 0.f, 0.f);
            if (gn < NNODES) v = *(const float4*)&in[(size_t)gn * K + ko + c4 * 4];
            if (RELU) {
                v.x = fmaxf(v.x, 0.f); v.y = fmaxf(v.y, 0.f);
                v.z = fmaxf(v.z, 0.f); v.w = fmaxf(v.w, 0.f);
            }
            float* dp = &xs[r * CHKP + c4 * 4];
            dp[0] = v.x; dp[1] = v.y; dp[2] = v.z; dp[3] = v.w;
        }
        __syncthreads();
        for (int kk = 0; kk < CHK; kk++) {
            float xk = xs[nloc * CHKP + kk];
            const float* Wr = &W[(size_t)(ko + kk) * 64 + jhalf * 32];
#pragma unroll
            for (int j = 0; j < 32; j++) acc[j] = fmaf(xk, Wr[j], acc[j]);
        }
    }

    if (node < NNODES) {
        float dv = dinv[node];
        float dv2 = dv * dv;
        float* tp = &t_out[(size_t)node * 64 + jhalf * 32];
        float* ap = &agg[(size_t)node * 64 + jhalf * 32];
#pragma unroll
        for (int j4 = 0; j4 < 8; j4++) {
            float4 tv = make_float4(acc[j4*4], acc[j4*4+1], acc[j4*4+2], acc[j4*4+3]);
            *(float4*)&tp[j4 * 4] = tv;
            float4 av;
            av.x = bias[jhalf*32 + j4*4 + 0] + tv.x * dv2;
            av.y = bias[jhalf*32 + j4*4 + 1] + tv.y * dv2;
            av.z = bias[jhalf*32 + j4*4 + 2] + tv.z * dv2;
            av.w = bias[jhalf*32 + j4*4 + 3] + tv.w * dv2;
            *(float4*)&ap[j4 * 4] = av;
        }
    }
}

// ---------- aggregation: one block per bucket, LDS accumulators ----------

__global__ __launch_bounds__(256) void k_agg(const float* __restrict__ t, const int* __restrict__ bbase,
                                             const int2* __restrict__ ebin, float* __restrict__ agg) {
    __shared__ float acc[NPB * 64];   // 32 KB
    int tid = threadIdx.x, lane = tid & 63, wid = tid >> 6;
    int j = blockIdx.x;
    for (int i = tid; i < NPB * 64; i += 256) acc[i] = 0.f;
    __syncthreads();
    int lo = bbase[j], hi = bbase[j + 1];
    for (int base = lo + wid * 64; base < hi; base += 256) {
        int idx = base + lane;
        int2 rec = make_int2(0, 0);
        if (idx < hi) rec = ebin[idx];
        int nsub = min(64, hi - base);
        for (int sub = 0; sub < nsub; sub++) {
            int v = __shfl(rec.x, sub);
            float w = __int_as_float(__shfl(rec.y, sub));
            int s = v & 0x1FFFF;
            int dloc = v >> 17;
            float tv = t[(size_t)s * 64 + lane];        // coalesced 256B row gather
            atomicAdd(&acc[dloc * 64 + lane], w * tv);  // ds_add_f32, no return
        }
    }
    __syncthreads();
    int node0 = j * NPB;
    for (int r = wid; r < NPB; r += 4) {
        int node = node0 + r;
        if (node >= NNODES) break;
        float* ap = &agg[(size_t)node * 64 + lane];
        *ap += acc[r * 64 + lane];
    }
}

// ---------- pooling + head ----------

#define POOL_CHUNK 256
__global__ __launch_bounds__(256) void k_pool(const float* __restrict__ h, const int* __restrict__ batch,
                                              float* pooled, float* gcnt) {
    int w = (blockIdx.x * 256 + threadIdx.x) >> 6;
    int lane = threadIdx.x & 63;
    int start = w * POOL_CHUNK;
    if (start >= NNODES) return;
    int end = min(start + POOL_CHUNK, NNODES);
    int g = batch[start];
    float acc = 0.f;
    int cn = 0;
    for (int i = start; i < end; i++) {
        int gi = batch[i];
        if (gi != g) {
            atomicAdd(&pooled[g * 64 + lane], acc);
            if (lane == 0) atomicAdd(&gcnt[g], (float)cn);
            g = gi; acc = 0.f; cn = 0;
        }
        acc += fmaxf(h[i * 64 + lane], 0.f);   // relu of layer-3 output
        cn++;
    }
    atomicAdd(&pooled[g * 64 + lane], acc);
    if (lane == 0) atomicAdd(&gcnt[g], (float)cn);
}

__global__ __launch_bounds__(256) void k_final(const float* __restrict__ pooled, const float* __restrict__ gcnt,
                                               const float* __restrict__ Wl, const float* __restrict__ bl,
                                               float* __restrict__ out) {
    int g = (blockIdx.x * 256 + threadIdx.x) >> 6;
    int lane = threadIdx.x & 63;
    if (g >= NGRAPHS) return;
    float c = fmaxf(gcnt[g], 1.f);
    float v = pooled[g * 64 + lane] / c * Wl[lane];
#pragma unroll
    for (int off = 32; off; off >>= 1) v += __shfl_down(v, off);
    if (lane == 0) out[g] = v + bl[0];
}

// ---------- launch ----------

extern "C" void kernel_launch(void* const* d_in, const int* in_sizes, int n_in,
                              void* d_out, int out_size, void* d_ws, size_t ws_size,
                              hipStream_t stream) {
    const float* x  = (const float*)d_in[0];
    const int* ei   = (const int*)d_in[1];
    const int* batch = (const int*)d_in[2];
    const float* W1 = (const float*)d_in[3];
    const float* b1 = (const float*)d_in[4];
    const float* W2 = (const float*)d_in[5];
    const float* b2 = (const float*)d_in[6];
    const float* W3 = (const float*)d_in[7];
    const float* b3 = (const float*)d_in[8];
    const float* Wl = (const float*)d_in[9];
    const float* bl = (const float*)d_in[10];
    const int* src = ei;
    const int* dst = ei + NEDGES;

    char* ws = (char*)d_ws;
    size_t off = 0;
    auto alloc = [&](size_t bytes) { void* p = ws + off; off += (bytes + 255) & ~size_t(255); return p; };
    float*  A      = (float*)alloc((size_t)NNODES * 64 * 4);
    float*  B      = (float*)alloc((size_t)NNODES * 64 * 4);
    int2*   ebin   = (int2*)alloc((size_t)NEDGES * 8);
    float*  dinv   = (float*)alloc((size_t)NNODES * 4);
    int*    cnt    = (int*)alloc((size_t)NNODES * 4);
    int*    cntmat = (int*)alloc((size_t)NBLKA * NBUCK * 4);
    int*    offmat = (int*)alloc((size_t)NBLKA * NBUCK * 4);
    int*    bbase  = (int*)alloc((NBUCK + 1) * 4);
    float*  pooled = (float*)alloc(NGRAPHS * 64 * 4);
    float*  gcnt   = (float*)alloc(NGRAPHS * 4);
    float*  out    = (float*)d_out;

    const int NB_N  = (NNODES + 255) / 256;
    const int NB_E  = (NEDGES + 255) / 256;
    const int NB_MM = (NNODES + 127) / 128;
    const int NB_PL = ((NNODES + POOL_CHUNK - 1) / POOL_CHUNK + 3) / 4;

    k_init<<<NB_N, 256, 0, stream>>>(cnt, pooled, gcnt);
    k_count<<<NB_E, 256, 0, stream>>>(dst, cnt);
    k_dinv<<<NB_N, 256, 0, stream>>>(cnt, dinv);
    k_hist<<<NBLKA, 256, 0, stream>>>(dst, cntmat);
    k_offs<<<1, 256, 0, stream>>>(cntmat, offmat, bbase);
    k_bin<<<NBLKA, 256, 0, stream>>>(src, dst, dinv, offmat, ebin);

    // layer 1: x[N,128] -> A (transform), B (agg init); then aggregate into B
    k_mm<128, false><<<NB_MM, 256, 0, stream>>>(x, W1, b1, dinv, A, B);
    k_agg<<<NBUCK, 256, 0, stream>>>(A, bbase, ebin, B);
    // layer 2 (relu on read)
    k_mm<64, true><<<NB_MM, 256, 0, stream>>>(B, W2, b2, dinv, A, B);
    k_agg<<<NBUCK, 256, 0, stream>>>(A, bbase, ebin, B);
    // layer 3
    k_mm<64, true><<<NB_MM, 256, 0, stream>>>(B, W3, b3, dinv, A, B);
    k_agg<<<NBUCK, 256, 0, stream>>>(A, bbase, ebin, B);

    k_pool<<<NB_PL, 256, 0, stream>>>(B, batch, pooled, gcnt);
    k_final<<<(NGRAPHS * 64 + 255) / 256, 256, 0, stream>>>(pooled, gcnt, Wl, bl, out);
}

// Round 6
// 4500.078 us; speedup vs baseline: 1.0774x; 1.0774x over previous
//
#include <hip/hip_runtime.h>

#define NNODES 100000
#define NEDGES 3200000
#define NFEATS 128
#define HID 64
#define NGRAPHS 64
#define NPB 128                              // nodes per bucket
#define NBUCK ((NNODES + NPB - 1) / NPB)     // 782
#define NBLKA 128                            // binning blocks
#define EPB (NEDGES / NBLKA)                 // 25000 edges per binning block
#define EPW 16                               // edges in flight per wave (k_agg)

// ---------- setup ----------

__global__ __launch_bounds__(256) void k_init(int* cnt, float* pooled, float* gcnt) {
    int i = blockIdx.x * 256 + threadIdx.x;
    if (i < NNODES) cnt[i] = 0;
    if (i < NGRAPHS * HID) pooled[i] = 0.f;
    if (i < NGRAPHS) gcnt[i] = 0.f;
}

__global__ __launch_bounds__(256) void k_count(const int* __restrict__ dst, int* __restrict__ cnt) {
    int e = blockIdx.x * 256 + threadIdx.x;
    if (e < NEDGES) atomicAdd(&cnt[dst[e]], 1);
}

__global__ __launch_bounds__(256) void k_dinv(const int* __restrict__ cnt, float* __restrict__ dinv) {
    int i = blockIdx.x * 256 + threadIdx.x;
    if (i < NNODES) dinv[i] = rsqrtf((float)(cnt[i] + 1));   // +1 self loop, always > 0
}

// per-block LDS histogram over buckets -> cntmat[b][j]. zero global atomics.
__global__ __launch_bounds__(256) void k_hist(const int* __restrict__ dst, int* __restrict__ cntmat) {
    __shared__ int h[NBUCK];
    for (int j = threadIdx.x; j < NBUCK; j += 256) h[j] = 0;
    __syncthreads();
    int e0 = blockIdx.x * EPB;
    for (int i = threadIdx.x; i < EPB; i += 256) atomicAdd(&h[dst[e0 + i] >> 7], 1);
    __syncthreads();
    for (int j = threadIdx.x; j < NBUCK; j += 256) cntmat[blockIdx.x * NBUCK + j] = h[j];
}

// single block: bucket totals -> exclusive bases (wave scan) -> per-(block,bucket) offsets
__global__ __launch_bounds__(256) void k_offs(const int* __restrict__ cntmat, int* __restrict__ offmat,
                                              int* __restrict__ bbase) {
    __shared__ int tot[NBUCK];
    __shared__ int bex[NBUCK];
    int tid = threadIdx.x;
    for (int j = tid; j < NBUCK; j += 256) {
        int s = 0;
        for (int b = 0; b < NBLKA; b++) s += cntmat[b * NBUCK + j];
        tot[j] = s;
    }
    __syncthreads();
    if (tid < 64) {   // wave 0: exclusive scan over 782 totals
        int run = 0;
        for (int c = 0; c < NBUCK; c += 64) {
            int j = c + tid;
            int own = (j < NBUCK) ? tot[j] : 0;
            int v = own;
            for (int off = 1; off < 64; off <<= 1) {
                int u = __shfl_up(v, off);
                if (tid >= off) v += u;
            }
            if (j < NBUCK) bex[j] = run + v - own;
            run += __shfl(v, 63);
        }
    }
    __syncthreads();
    for (int j = tid; j < NBUCK; j += 256) {
        int run = bex[j];
        bbase[j] = run;
        for (int b = 0; b < NBLKA; b++) { offmat[b * NBUCK + j] = run; run += cntmat[b * NBUCK + j]; }
    }
    if (tid == 0) bbase[NBUCK] = NEDGES;
}

// place edges: LDS cursors (no global atomics), 8B packed record (s|dloc<<17, w)
__global__ __launch_bounds__(256) void k_bin(const int* __restrict__ src, const int* __restrict__ dst,
                                             const float* __restrict__ dinv, const int* __restrict__ offmat,
                                             int2* __restrict__ ebin) {
    __shared__ int cur[NBUCK];
    int b = blockIdx.x;
    for (int j = threadIdx.x; j < NBUCK; j += 256) cur[j] = offmat[b * NBUCK + j];
    __syncthreads();
    int e0 = b * EPB;
    for (int i = threadIdx.x; i < EPB; i += 256) {
        int s = src[e0 + i], d = dst[e0 + i];
        int p = atomicAdd(&cur[d >> 7], 1);
        float w = dinv[s] * dinv[d];
        ebin[p] = make_int2(s | ((d & (NPB - 1)) << 17), __float_as_int(w));
    }
}

// ---------- transform (GEMV per node, wave-uniform W -> s_load) ----------

#define CHK 32
#define CHKP 33   // +1 pad: conflict-free stride

// block = 128 nodes x 2 col-halves (256 threads). Thread owns 32 output cols
// of one node; acc in 32 VGPRs. x staged coalesced to LDS per 32-k chunk.
// Safe when in == agg: block reads exactly the rows it writes, and every
// global read precedes the final __syncthreads().
template <int K, bool RELU>
__global__ __launch_bounds__(256) void k_mm(const float* __restrict__ in, const float* __restrict__ W,
                                            const float* __restrict__ bias, const float* __restrict__ dinv,
                                            float* __restrict__ t_out, float* __restrict__ agg) {
    __shared__ float xs[128 * CHKP];
    const int tid = threadIdx.x;
    const int lane = tid & 63;
    const int wid = tid >> 6;
    const int jhalf = __builtin_amdgcn_readfirstlane(wid & 1);
    const int nloc = (wid >> 1) * 64 + lane;   // 0..127 local node
    const int node0 = blockIdx.x * 128;
    const int node = node0 + nloc;

    float acc[32];
#pragma unroll
    for (int j = 0; j < 32; j++) acc[j] = 0.f;

    const int c4 = tid & 7;     // float4 slot in row (8 per 32-float chunk)
    const int r0 = tid >> 3;    // 0..31

    for (int ko = 0; ko < K; ko += CHK) {
        __syncthreads();
#pragma unroll
        for (int s = 0; s < 4; s++) {
            int r = r0 + s * 32;
            int gn = node0 + r;
            float4 v = make_float4(0.f, 0.f, 0.f, 0.f);
            if (gn < NNODES) v = *(const float4*)&in[(size_t)gn * K + ko + c4 * 4];
            if (RELU) {
                v.x = fmaxf(v.x, 0.f); v.y = fmaxf(v.y, 0.f);
                v.z = fmaxf(v.z, 0.f); v.w = fmaxf(v.w, 0.f);
            }
            float* dp = &xs[r * CHKP + c4 * 4];
            dp[0] = v.x; dp[1] = v.y; dp[2] = v.z; dp[3] = v.w;
        }
        __syncthreads();
        for (int kk = 0; kk < CHK; kk++) {
            float xk = xs[nloc * CHKP + kk];
            const float* Wr = &W[(size_t)(ko + kk) * 64 + jhalf * 32];
#pragma unroll
            for (int j = 0; j < 32; j++) acc[j] = fmaf(xk, Wr[j], acc[j]);
        }
    }

    if (node < NNODES) {
        float dv = dinv[node];
        float dv2 = dv * dv;
        float* tp = &t_out[(size_t)node * 64 + jhalf * 32];
        float* ap = &agg[(size_t)node * 64 + jhalf * 32];
#pragma unroll
        for (int j4 = 0; j4 < 8; j4++) {
            float4 tv = make_float4(acc[j4*4], acc[j4*4+1], acc[j4*4+2], acc[j4*4+3]);
            *(float4*)&tp[j4 * 4] = tv;
            float4 av;
            av.x = bias[jhalf*32 + j4*4 + 0] + tv.x * dv2;
            av.y = bias[jhalf*32 + j4*4 + 1] + tv.y * dv2;
            av.z = bias[jhalf*32 + j4*4 + 2] + tv.z * dv2;
            av.w = bias[jhalf*32 + j4*4 + 3] + tv.w * dv2;
            *(float4*)&ap[j4 * 4] = av;
        }
    }
}

// ---------- aggregation: block per bucket, LDS accumulators, 16 edges in flight/wave ----------

__global__ __launch_bounds__(256) void k_agg(const float* __restrict__ t, const int* __restrict__ bbase,
                                             const int2* __restrict__ ebin, float* __restrict__ agg) {
    __shared__ float acc[NPB * 64];   // 32 KB
    const int tid = threadIdx.x;
    const int lane = tid & 63;
    const int wid = __builtin_amdgcn_readfirstlane(tid >> 6);   // wave-uniform in SGPR
    const int j = blockIdx.x;
    for (int i = tid; i < NPB * 64; i += 256) acc[i] = 0.f;
    __syncthreads();
    const int lo = bbase[j], hi = bbase[j + 1];
    for (int base = lo + wid * EPW; base < hi; base += 4 * EPW) {
        int2 rec[EPW];
#pragma unroll
        for (int u = 0; u < EPW; u++) {
            int e = base + u;
            int2 r = ebin[min(e, hi - 1)];          // wave-uniform addr -> broadcast
            if (e >= hi) r.y = 0;                   // w = 0 on tail
            rec[u] = r;
        }
        float v[EPW];
#pragma unroll
        for (int u = 0; u < EPW; u++)               // 16 independent 256B row gathers
            v[u] = t[(size_t)(rec[u].x & 0x1FFFF) * 64 + lane];
#pragma unroll
        for (int u = 0; u < EPW; u++)               // ds_add, bank = lane%32 -> 2-way (free)
            atomicAdd(&acc[((rec[u].x >> 17) & 127) * 64 + lane],
                      __int_as_float(rec[u].y) * v[u]);
    }
    __syncthreads();
    int node0 = j * NPB;
    for (int r = wid; r < NPB; r += 4) {
        int node = node0 + r;
        if (node >= NNODES) break;
        agg[(size_t)node * 64 + lane] += acc[r * 64 + lane];
    }
}

// ---------- pooling + head ----------

#define POOL_CHUNK 256
__global__ __launch_bounds__(256) void k_pool(const float* __restrict__ h, const int* __restrict__ batch,
                                              float* pooled, float* gcnt) {
    int w = (blockIdx.x * 256 + threadIdx.x) >> 6;
    int lane = threadIdx.x & 63;
    int start = w * POOL_CHUNK;
    if (start >= NNODES) return;
    int end = min(start + POOL_CHUNK, NNODES);
    int g = batch[start];
    float acc = 0.f;
    int cn = 0;
    for (int i = start; i < end; i++) {
        int gi = batch[i];
        if (gi != g) {
            atomicAdd(&pooled[g * 64 + lane], acc);
            if (lane == 0) atomicAdd(&gcnt[g], (float)cn);
            g = gi; acc = 0.f; cn = 0;
        }
        acc += fmaxf(h[i * 64 + lane], 0.f);   // relu of layer-3 output
        cn++;
    }
    atomicAdd(&pooled[g * 64 + lane], acc);
    if (lane == 0) atomicAdd(&gcnt[g], (float)cn);
}

__global__ __launch_bounds__(256) void k_final(const float* __restrict__ pooled, const float* __restrict__ gcnt,
                                               const float* __restrict__ Wl, const float* __restrict__ bl,
                                               float* __restrict__ out) {
    int g = (blockIdx.x * 256 + threadIdx.x) >> 6;
    int lane = threadIdx.x & 63;
    if (g >= NGRAPHS) return;
    float c = fmaxf(gcnt[g], 1.f);
    float v = pooled[g * 64 + lane] / c * Wl[lane];
#pragma unroll
    for (int off = 32; off; off >>= 1) v += __shfl_down(v, off);
    if (lane == 0) out[g] = v + bl[0];
}

// ---------- launch ----------

extern "C" void kernel_launch(void* const* d_in, const int* in_sizes, int n_in,
                              void* d_out, int out_size, void* d_ws, size_t ws_size,
                              hipStream_t stream) {
    const float* x  = (const float*)d_in[0];
    const int* ei   = (const int*)d_in[1];
    const int* batch = (const int*)d_in[2];
    const float* W1 = (const float*)d_in[3];
    const float* b1 = (const float*)d_in[4];
    const float* W2 = (const float*)d_in[5];
    const float* b2 = (const float*)d_in[6];
    const float* W3 = (const float*)d_in[7];
    const float* b3 = (const float*)d_in[8];
    const float* Wl = (const float*)d_in[9];
    const float* bl = (const float*)d_in[10];
    const int* src = ei;
    const int* dst = ei + NEDGES;

    char* ws = (char*)d_ws;
    size_t off = 0;
    auto alloc = [&](size_t bytes) { void* p = ws + off; off += (bytes + 255) & ~size_t(255); return p; };
    float*  A      = (float*)alloc((size_t)NNODES * 64 * 4);
    float*  B      = (float*)alloc((size_t)NNODES * 64 * 4);
    int2*   ebin   = (int2*)alloc((size_t)NEDGES * 8);
    float*  dinv   = (float*)alloc((size_t)NNODES * 4);
    int*    cnt    = (int*)alloc((size_t)NNODES * 4);
    int*    cntmat = (int*)alloc((size_t)NBLKA * NBUCK * 4);
    int*    offmat = (int*)alloc((size_t)NBLKA * NBUCK * 4);
    int*    bbase  = (int*)alloc((NBUCK + 1) * 4);
    float*  pooled = (float*)alloc(NGRAPHS * 64 * 4);
    float*  gcnt   = (float*)alloc(NGRAPHS * 4);
    float*  out    = (float*)d_out;

    const int NB_N  = (NNODES + 255) / 256;
    const int NB_E  = (NEDGES + 255) / 256;
    const int NB_MM = (NNODES + 127) / 128;
    const int NB_PL = ((NNODES + POOL_CHUNK - 1) / POOL_CHUNK + 3) / 4;

    k_init<<<NB_N, 256, 0, stream>>>(cnt, pooled, gcnt);
    k_count<<<NB_E, 256, 0, stream>>>(dst, cnt);
    k_dinv<<<NB_N, 256, 0, stream>>>(cnt, dinv);
    k_hist<<<NBLKA, 256, 0, stream>>>(dst, cntmat);
    k_offs<<<1, 256, 0, stream>>>(cntmat, offmat, bbase);
    k_bin<<<NBLKA, 256, 0, stream>>>(src, dst, dinv, offmat, ebin);

    // layer 1: x[N,128] -> A (transform), B (agg init); then aggregate into B
    k_mm<128, false><<<NB_MM, 256, 0, stream>>>(x, W1, b1, dinv, A, B);
    k_agg<<<NBUCK, 256, 0, stream>>>(A, bbase, ebin, B);
    // layer 2 (relu on read)
    k_mm<64, true><<<NB_MM, 256, 0, stream>>>(B, W2, b2, dinv, A, B);
    k_agg<<<NBUCK, 256, 0, stream>>>(A, bbase, ebin, B);
    // layer 3
    k_mm<64, true><<<NB_MM, 256, 0, stream>>>(B, W3, b3, dinv, A, B);
    k_agg<<<NBUCK, 256, 0, stream>>>(A, bbase, ebin, B);

    k_pool<<<NB_PL, 256, 0, stream>>>(B, batch, pooled, gcnt);
    k_final<<<(NGRAPHS * 64 + 255) / 256, 256, 0, stream>>>(pooled, gcnt, Wl, bl, out);
}

// Round 7
// 869.599 us; speedup vs baseline: 5.5753x; 5.1749x over previous
//
#include <hip/hip_runtime.h>

#define NNODES 100000
#define NEDGES 3200000
#define NFEATS 128
#define HID 64
#define NGRAPHS 64
#define NPB 128                              // nodes per bucket
#define NBUCK ((NNODES + NPB - 1) / NPB)     // 782
#define NBLKA 128                            // binning blocks
#define EPB (NEDGES / NBLKA)                 // 25000 edges per binning block

// ---------- setup ----------

__global__ __launch_bounds__(256) void k_init(int* cnt, float* pooled, float* gcnt) {
    int i = blockIdx.x * 256 + threadIdx.x;
    if (i < NNODES) cnt[i] = 0;
    if (i < NGRAPHS * HID) pooled[i] = 0.f;
    if (i < NGRAPHS) gcnt[i] = 0.f;
}

__global__ __launch_bounds__(256) void k_count(const int* __restrict__ dst, int* __restrict__ cnt) {
    int e = blockIdx.x * 256 + threadIdx.x;
    if (e < NEDGES) atomicAdd(&cnt[dst[e]], 1);
}

// exclusive scan of cnt -> rowptr. 256 threads x 16 items = 4096/block.
__global__ __launch_bounds__(256) void k_scan1(const int* __restrict__ cnt, int* __restrict__ rowptr,
                                               int* __restrict__ bsums) {
    __shared__ int sh[256];
    int tid = threadIdx.x;
    int base = blockIdx.x * 4096 + tid * 16;
    int v[16];
    int s = 0;
#pragma unroll
    for (int p = 0; p < 16; p++) {
        int idx = base + p;
        int c = (idx < NNODES) ? cnt[idx] : 0;
        v[p] = s;
        s += c;
    }
    sh[tid] = s;
    __syncthreads();
    for (int off = 1; off < 256; off <<= 1) {
        int t = (tid >= off) ? sh[tid - off] : 0;
        __syncthreads();
        sh[tid] += t;
        __syncthreads();
    }
    int excl = tid ? sh[tid - 1] : 0;
#pragma unroll
    for (int p = 0; p < 16; p++) {
        int idx = base + p;
        if (idx < NNODES) rowptr[idx] = excl + v[p];
    }
    if (tid == 255) bsums[blockIdx.x] = sh[255];
}

__global__ void k_scan2(int* bsums, int nb) {
    int run = 0;
    for (int b = 0; b < nb; b++) { int t = bsums[b]; bsums[b] = run; run += t; }
}

__global__ __launch_bounds__(256) void k_scan3(const int* __restrict__ cnt, int* __restrict__ rowptr,
                                               float* __restrict__ dinv, const int* __restrict__ bsums) {
    int i = blockIdx.x * 256 + threadIdx.x;
    if (i >= NNODES) return;
    rowptr[i] += bsums[i >> 12];
    dinv[i] = rsqrtf((float)(cnt[i] + 1));   // +1 self loop, always > 0
}

// per-block LDS histogram over buckets -> cntmat[b][j]. zero global atomics.
__global__ __launch_bounds__(256) void k_hist(const int* __restrict__ dst, int* __restrict__ cntmat) {
    __shared__ int h[NBUCK];
    for (int j = threadIdx.x; j < NBUCK; j += 256) h[j] = 0;
    __syncthreads();
    int e0 = blockIdx.x * EPB;
    for (int i = threadIdx.x; i < EPB; i += 256) atomicAdd(&h[dst[e0 + i] >> 7], 1);
    __syncthreads();
    for (int j = threadIdx.x; j < NBUCK; j += 256) cntmat[blockIdx.x * NBUCK + j] = h[j];
}

// single block: bucket totals -> exclusive bases (wave scan) -> per-(block,bucket) offsets
__global__ __launch_bounds__(256) void k_offs(const int* __restrict__ cntmat, int* __restrict__ offmat,
                                              int* __restrict__ bbase) {
    __shared__ int tot[NBUCK];
    __shared__ int bex[NBUCK];
    int tid = threadIdx.x;
    for (int j = tid; j < NBUCK; j += 256) {
        int s = 0;
        for (int b = 0; b < NBLKA; b++) s += cntmat[b * NBUCK + j];
        tot[j] = s;
    }
    __syncthreads();
    if (tid < 64) {   // wave 0: exclusive scan over 782 totals
        int run = 0;
        for (int c = 0; c < NBUCK; c += 64) {
            int j = c + tid;
            int own = (j < NBUCK) ? tot[j] : 0;
            int v = own;
            for (int off = 1; off < 64; off <<= 1) {
                int u = __shfl_up(v, off);
                if (tid >= off) v += u;
            }
            if (j < NBUCK) bex[j] = run + v - own;
            run += __shfl(v, 63);
        }
    }
    __syncthreads();
    for (int j = tid; j < NBUCK; j += 256) {
        int run = bex[j];
        bbase[j] = run;
        for (int b = 0; b < NBLKA; b++) { offmat[b * NBUCK + j] = run; run += cntmat[b * NBUCK + j]; }
    }
    if (tid == 0) bbase[NBUCK] = NEDGES;
}

// place edges into bucket-local regions: LDS cursors, packed (s|dloc<<17, w)
__global__ __launch_bounds__(256) void k_bin(const int* __restrict__ src, const int* __restrict__ dst,
                                             const float* __restrict__ dinv, const int* __restrict__ offmat,
                                             int2* __restrict__ ebin) {
    __shared__ int cur[NBUCK];
    int b = blockIdx.x;
    for (int j = threadIdx.x; j < NBUCK; j += 256) cur[j] = offmat[b * NBUCK + j];
    __syncthreads();
    int e0 = b * EPB;
    for (int i = threadIdx.x; i < EPB; i += 256) {
        int s = src[e0 + i], d = dst[e0 + i];
        int p = atomicAdd(&cur[d >> 7], 1);
        float w = dinv[s] * dinv[d];
        ebin[p] = make_int2(s | ((d & (NPB - 1)) << 17), __float_as_int(w));
    }
}

// within-bucket counting sort to per-node CSR order. Reads sequential,
// writes confined to the bucket's contiguous ~32KB colw window (L2-resident).
__global__ __launch_bounds__(256) void k_sort(const int2* __restrict__ ebin, const int* __restrict__ bbase,
                                              const int* __restrict__ rowptr, float2* __restrict__ colw) {
    __shared__ int cur[NPB];
    int j = blockIdx.x;
    int node0 = j * NPB;
    for (int i = threadIdx.x; i < NPB; i += 256)
        cur[i] = (node0 + i < NNODES) ? rowptr[node0 + i] : 0;
    __syncthreads();
    int lo = bbase[j], hi = bbase[j + 1];
    for (int i = lo + threadIdx.x; i < hi; i += 256) {
        int2 r = ebin[i];
        int dloc = (r.x >> 17) & (NPB - 1);
        int p = atomicAdd(&cur[dloc], 1);
        colw[p] = make_float2(__int_as_float(r.x & 0x1FFFF), __int_as_float(r.y));
    }
}

// ---------- transform (GEMV per node, wave-uniform W -> s_load) ----------

#define CHK 32
#define CHKP 33   // +1 pad: conflict-free stride

// block = 128 nodes x 2 col-halves (256 threads). Thread owns 32 output cols
// of one node; acc in 32 VGPRs. x staged coalesced to LDS per 32-k chunk.
// Safe when in == agg: block reads exactly the rows it writes, and every
// global read precedes the final __syncthreads().
template <int K, bool RELU>
__global__ __launch_bounds__(256) void k_mm(const float* __restrict__ in, const float* __restrict__ W,
                                            const float* __restrict__ bias, const float* __restrict__ dinv,
                                            float* __restrict__ t_out, float* __restrict__ agg) {
    __shared__ float xs[128 * CHKP];
    const int tid = threadIdx.x;
    const int lane = tid & 63;
    const int wid = tid >> 6;
    const int jhalf = __builtin_amdgcn_readfirstlane(wid & 1);
    const int nloc = (wid >> 1) * 64 + lane;   // 0..127 local node
    const int node0 = blockIdx.x * 128;
    const int node = node0 + nloc;

    float acc[32];
#pragma unroll
    for (int j = 0; j < 32; j++) acc[j] = 0.f;

    const int c4 = tid & 7;     // float4 slot in row (8 per 32-float chunk)
    const int r0 = tid >> 3;    // 0..31

    for (int ko = 0; ko < K; ko += CHK) {
        __syncthreads();
#pragma unroll
        for (int s = 0; s < 4; s++) {
            int r = r0 + s * 32;
            int gn = node0 + r;
            float4 v = make_float4(0.f, 0.f, 0.f, 0.f);
            if (gn < NNODES) v = *(const float4*)&in[(size_t)gn * K + ko + c4 * 4];
            if (RELU) {
                v.x = fmaxf(v.x, 0.f); v.y = fmaxf(v.y, 0.f);
                v.z = fmaxf(v.z, 0.f); v.w = fmaxf(v.w, 0.f);
            }
            float* dp = &xs[r * CHKP + c4 * 4];
            dp[0] = v.x; dp[1] = v.y; dp[2] = v.z; dp[3] = v.w;
        }
        __syncthreads();
        for (int kk = 0; kk < CHK; kk++) {
            float xk = xs[nloc * CHKP + kk];
            const float* Wr = &W[(size_t)(ko + kk) * 64 + jhalf * 32];
#pragma unroll
            for (int j = 0; j < 32; j++) acc[j] = fmaf(xk, Wr[j], acc[j]);
        }
    }

    if (node < NNODES) {
        float dv = dinv[node];
        float dv2 = dv * dv;
        float* tp = &t_out[(size_t)node * 64 + jhalf * 32];
        float* ap = &agg[(size_t)node * 64 + jhalf * 32];
#pragma unroll
        for (int j4 = 0; j4 < 8; j4++) {
            float4 tv = make_float4(acc[j4*4], acc[j4*4+1], acc[j4*4+2], acc[j4*4+3]);
            *(float4*)&tp[j4 * 4] = tv;
            float4 av;
            av.x = bias[jhalf*32 + j4*4 + 0] + tv.x * dv2;
            av.y = bias[jhalf*32 + j4*4 + 1] + tv.y * dv2;
            av.z = bias[jhalf*32 + j4*4 + 2] + tv.z * dv2;
            av.w = bias[jhalf*32 + j4*4 + 3] + tv.w * dv2;
            *(float4*)&ap[j4 * 4] = av;
        }
    }
}

// ---------- aggregation: wave per node, 4 edges in flight, no LDS (max TLP) ----------

__global__ __launch_bounds__(256) void k_agg(const float* __restrict__ t, const int* __restrict__ rowptr,
                                             const int* __restrict__ cnt, const float2* __restrict__ colw,
                                             float* __restrict__ agg) {
    int w = (blockIdx.x * 256 + threadIdx.x) >> 6;   // node
    int lane = threadIdx.x & 63;
    if (w >= NNODES) return;
    int qg = lane >> 4;      // edge-slot group 0..3
    int ql = lane & 15;      // float4 slot within the 64-float row
    int start = rowptr[w];
    int n = cnt[w];
    float4 acc = make_float4(0.f, 0.f, 0.f, 0.f);
    for (int e = qg; e < n; e += 4) {
        float2 p = colw[start + e];
        float4 v = *(const float4*)&t[(size_t)__float_as_int(p.x) * 64 + ql * 4];
        acc.x = fmaf(p.y, v.x, acc.x);
        acc.y = fmaf(p.y, v.y, acc.y);
        acc.z = fmaf(p.y, v.z, acc.z);
        acc.w = fmaf(p.y, v.w, acc.w);
    }
    // reduce the 4 edge-slot groups (lanes l, l^16, l^32, l^48)
    acc.x += __shfl_xor(acc.x, 16); acc.y += __shfl_xor(acc.y, 16);
    acc.z += __shfl_xor(acc.z, 16); acc.w += __shfl_xor(acc.w, 16);
    acc.x += __shfl_xor(acc.x, 32); acc.y += __shfl_xor(acc.y, 32);
    acc.z += __shfl_xor(acc.z, 32); acc.w += __shfl_xor(acc.w, 32);
    if (qg == 0) {
        float4* ap = (float4*)&agg[(size_t)w * 64 + ql * 4];
        float4 o = *ap;
        o.x += acc.x; o.y += acc.y; o.z += acc.z; o.w += acc.w;
        *ap = o;
    }
}

// ---------- pooling + head ----------

#define POOL_CHUNK 256
__global__ __launch_bounds__(256) void k_pool(const float* __restrict__ h, const int* __restrict__ batch,
                                              float* pooled, float* gcnt) {
    int w = (blockIdx.x * 256 + threadIdx.x) >> 6;
    int lane = threadIdx.x & 63;
    int start = w * POOL_CHUNK;
    if (start >= NNODES) return;
    int end = min(start + POOL_CHUNK, NNODES);
    int g = batch[start];
    float acc = 0.f;
    int cn = 0;
    for (int i = start; i < end; i++) {
        int gi = batch[i];
        if (gi != g) {
            atomicAdd(&pooled[g * 64 + lane], acc);
            if (lane == 0) atomicAdd(&gcnt[g], (float)cn);
            g = gi; acc = 0.f; cn = 0;
        }
        acc += fmaxf(h[i * 64 + lane], 0.f);   // relu of layer-3 output
        cn++;
    }
    atomicAdd(&pooled[g * 64 + lane], acc);
    if (lane == 0) atomicAdd(&gcnt[g], (float)cn);
}

__global__ __launch_bounds__(256) void k_final(const float* __restrict__ pooled, const float* __restrict__ gcnt,
                                               const float* __restrict__ Wl, const float* __restrict__ bl,
                                               float* __restrict__ out) {
    int g = (blockIdx.x * 256 + threadIdx.x) >> 6;
    int lane = threadIdx.x & 63;
    if (g >= NGRAPHS) return;
    float c = fmaxf(gcnt[g], 1.f);
    float v = pooled[g * 64 + lane] / c * Wl[lane];
#pragma unroll
    for (int off = 32; off; off >>= 1) v += __shfl_down(v, off);
    if (lane == 0) out[g] = v + bl[0];
}

// ---------- launch ----------

extern "C" void kernel_launch(void* const* d_in, const int* in_sizes, int n_in,
                              void* d_out, int out_size, void* d_ws, size_t ws_size,
                              hipStream_t stream) {
    const float* x  = (const float*)d_in[0];
    const int* ei   = (const int*)d_in[1];
    const int* batch = (const int*)d_in[2];
    const float* W1 = (const float*)d_in[3];
    const float* b1 = (const float*)d_in[4];
    const float* W2 = (const float*)d_in[5];
    const float* b2 = (const float*)d_in[6];
    const float* W3 = (const float*)d_in[7];
    const float* b3 = (const float*)d_in[8];
    const float* Wl = (const float*)d_in[9];
    const float* bl = (const float*)d_in[10];
    const int* src = ei;
    const int* dst = ei + NEDGES;

    char* ws = (char*)d_ws;
    size_t off = 0;
    auto alloc = [&](size_t bytes) { void* p = ws + off; off += (bytes + 255) & ~size_t(255); return p; };
    float*  A      = (float*)alloc((size_t)NNODES * 64 * 4);
    float*  B      = (float*)alloc((size_t)NNODES * 64 * 4);
    float2* colw   = (float2*)alloc((size_t)NEDGES * 8);
    float*  dinv   = (float*)alloc((size_t)NNODES * 4);
    int*    cnt    = (int*)alloc((size_t)NNODES * 4);
    int*    rowptr = (int*)alloc((size_t)NNODES * 4);
    int*    bsums  = (int*)alloc(32 * 4);
    int*    cntmat = (int*)alloc((size_t)NBLKA * NBUCK * 4);
    int*    offmat = (int*)alloc((size_t)NBLKA * NBUCK * 4);
    int*    bbase  = (int*)alloc((NBUCK + 1) * 4);
    float*  pooled = (float*)alloc(NGRAPHS * 64 * 4);
    float*  gcnt   = (float*)alloc(NGRAPHS * 4);
    float*  out    = (float*)d_out;
    int2*   ebin   = (int2*)A;   // bucket staging aliases A (dead before layer-1 k_mm writes A)

    const int NB_N  = (NNODES + 255) / 256;
    const int NB_E  = (NEDGES + 255) / 256;
    const int NB_SC = (NNODES + 4095) / 4096;
    const int NB_MM = (NNODES + 127) / 128;
    const int NB_W  = ((size_t)NNODES * 64 + 255) / 256;
    const int NB_PL = ((NNODES + POOL_CHUNK - 1) / POOL_CHUNK + 3) / 4;

    k_init<<<NB_N, 256, 0, stream>>>(cnt, pooled, gcnt);
    k_count<<<NB_E, 256, 0, stream>>>(dst, cnt);
    k_scan1<<<NB_SC, 256, 0, stream>>>(cnt, rowptr, bsums);
    k_scan2<<<1, 1, 0, stream>>>(bsums, NB_SC);
    k_scan3<<<NB_N, 256, 0, stream>>>(cnt, rowptr, dinv, bsums);
    k_hist<<<NBLKA, 256, 0, stream>>>(dst, cntmat);
    k_offs<<<1, 256, 0, stream>>>(cntmat, offmat, bbase);
    k_bin<<<NBLKA, 256, 0, stream>>>(src, dst, dinv, offmat, ebin);
    k_sort<<<NBUCK, 256, 0, stream>>>(ebin, bbase, rowptr, colw);

    // layer 1: x[N,128] -> A (transform), B (agg init); then aggregate into B
    k_mm<128, false><<<NB_MM, 256, 0, stream>>>(x, W1, b1, dinv, A, B);
    k_agg<<<NB_W, 256, 0, stream>>>(A, rowptr, cnt, colw, B);
    // layer 2 (relu on read)
    k_mm<64, true><<<NB_MM, 256, 0, stream>>>(B, W2, b2, dinv, A, B);
    k_agg<<<NB_W, 256, 0, stream>>>(A, rowptr, cnt, colw, B);
    // layer 3
    k_mm<64, true><<<NB_MM, 256, 0, stream>>>(B, W3, b3, dinv, A, B);
    k_agg<<<NB_W, 256, 0, stream>>>(A, rowptr, cnt, colw, B);

    k_pool<<<NB_PL, 256, 0, stream>>>(B, batch, pooled, gcnt);
    k_final<<<(NGRAPHS * 64 + 255) / 256, 256, 0, stream>>>(pooled, gcnt, Wl, bl, out);
}

// Round 8
// 714.420 us; speedup vs baseline: 6.7863x; 1.2172x over previous
//
#include <hip/hip_runtime.h>

#define NNODES 100000
#define NEDGES 3200000
#define NFEATS 128
#define HID 64
#define NGRAPHS 64
#define NPB 128                              // nodes per bucket
#define NBUCK ((NNODES + NPB - 1) / NPB)     // 782
#define NBLKA 128                            // binning blocks
#define EPB (NEDGES / NBLKA)                 // 25000 edges per binning block

// ---------- setup ----------

__global__ __launch_bounds__(256) void k_init(float* pooled, float* gcnt) {
    int i = blockIdx.x * 256 + threadIdx.x;
    if (i < NGRAPHS * HID) pooled[i] = 0.f;
    if (i < NGRAPHS) gcnt[i] = 0.f;
}

// per-block LDS histogram over buckets -> cntmat[b][j]. zero global atomics.
__global__ __launch_bounds__(256) void k_hist(const int* __restrict__ dst, int* __restrict__ cntmat) {
    __shared__ int h[NBUCK];
    for (int j = threadIdx.x; j < NBUCK; j += 256) h[j] = 0;
    __syncthreads();
    int e0 = blockIdx.x * EPB;
    for (int i = threadIdx.x; i < EPB; i += 256) atomicAdd(&h[dst[e0 + i] >> 7], 1);
    __syncthreads();
    for (int j = threadIdx.x; j < NBUCK; j += 256) cntmat[blockIdx.x * NBUCK + j] = h[j];
}

// single block: bucket totals -> exclusive bases (wave scan) -> per-(block,bucket) offsets
__global__ __launch_bounds__(256) void k_offs(const int* __restrict__ cntmat, int* __restrict__ offmat,
                                              int* __restrict__ bbase) {
    __shared__ int tot[NBUCK];
    __shared__ int bex[NBUCK];
    int tid = threadIdx.x;
    for (int j = tid; j < NBUCK; j += 256) {
        int s = 0;
        for (int b = 0; b < NBLKA; b++) s += cntmat[b * NBUCK + j];
        tot[j] = s;
    }
    __syncthreads();
    if (tid < 64) {   // wave 0: exclusive scan over 782 totals
        int run = 0;
        for (int c = 0; c < NBUCK; c += 64) {
            int j = c + tid;
            int own = (j < NBUCK) ? tot[j] : 0;
            int v = own;
            for (int off = 1; off < 64; off <<= 1) {
                int u = __shfl_up(v, off);
                if (tid >= off) v += u;
            }
            if (j < NBUCK) bex[j] = run + v - own;
            run += __shfl(v, 63);
        }
    }
    __syncthreads();
    for (int j = tid; j < NBUCK; j += 256) {
        int run = bex[j];
        bbase[j] = run;
        for (int b = 0; b < NBLKA; b++) { offmat[b * NBUCK + j] = run; run += cntmat[b * NBUCK + j]; }
    }
    if (tid == 0) bbase[NBUCK] = NEDGES;
}

// place edges into bucket-local regions: LDS cursors, 4B packed record s|dloc<<17
__global__ __launch_bounds__(256) void k_bin(const int* __restrict__ src, const int* __restrict__ dst,
                                             const int* __restrict__ offmat, int* __restrict__ ebin) {
    __shared__ int cur[NBUCK];
    int b = blockIdx.x;
    for (int j = threadIdx.x; j < NBUCK; j += 256) cur[j] = offmat[b * NBUCK + j];
    __syncthreads();
    int e0 = b * EPB;
    for (int i = threadIdx.x; i < EPB; i += 256) {
        int s = src[e0 + i], d = dst[e0 + i];
        int p = atomicAdd(&cur[d >> 7], 1);
        ebin[p] = s | ((d & (NPB - 1)) << 17);
    }
}

// per bucket: LDS per-node histogram + scan -> cnt, rowptr, dinv (no global atomics)
__global__ __launch_bounds__(256) void k_cnt2(const int* __restrict__ ebin, const int* __restrict__ bbase,
                                              int* __restrict__ cnt, int* __restrict__ rowptr,
                                              float* __restrict__ dinv) {
    __shared__ int h[NPB];
    __shared__ int sc[NPB];
    int j = blockIdx.x;
    int tid = threadIdx.x;
    if (tid < NPB) h[tid] = 0;
    __syncthreads();
    int lo = bbase[j], hi = bbase[j + 1];
    for (int i = lo + tid; i < hi; i += 256) atomicAdd(&h[ebin[i] >> 17], 1);
    __syncthreads();
    if (tid < 64) {   // wave 0: exclusive scan over 128 node counts
        int run = 0;
        for (int c = 0; c < NPB; c += 64) {
            int own = h[c + tid];
            int v = own;
            for (int off = 1; off < 64; off <<= 1) {
                int u = __shfl_up(v, off);
                if (tid >= off) v += u;
            }
            sc[c + tid] = run + v - own;
            run += __shfl(v, 63);
        }
    }
    __syncthreads();
    int node = j * NPB + tid;
    if (tid < NPB && node < NNODES) {
        int c = h[tid];
        cnt[node] = c;
        rowptr[node] = lo + sc[tid];
        dinv[node] = rsqrtf((float)(c + 1));   // +1 self loop, always > 0
    }
}

// within-bucket counting sort to per-node CSR order; w computed here.
// Writes confined to the bucket's contiguous ~32KB colw window (L2-resident).
__global__ __launch_bounds__(256) void k_sort(const int* __restrict__ ebin, const int* __restrict__ bbase,
                                              const int* __restrict__ rowptr, const float* __restrict__ dinv,
                                              float2* __restrict__ colw) {
    __shared__ int cur[NPB];
    int j = blockIdx.x;
    int node0 = j * NPB;
    int tid = threadIdx.x;
    if (tid < NPB) cur[tid] = (node0 + tid < NNODES) ? rowptr[node0 + tid] : 0;
    __syncthreads();
    int lo = bbase[j], hi = bbase[j + 1];
    for (int i = lo + tid; i < hi; i += 256) {
        int r = ebin[i];
        int s = r & 0x1FFFF;
        int dloc = r >> 17;
        float w = dinv[s] * dinv[node0 + dloc];
        int p = atomicAdd(&cur[dloc], 1);
        colw[p] = make_float2(__int_as_float(s), w);
    }
}

// ---------- transform (GEMV per node, wave-uniform W -> s_load) ----------

#define CHK 32
#define CHKP 33   // +1 pad: conflict-free stride

// block = 128 nodes x 2 col-halves (256 threads). Thread owns 32 output cols
// of one node; acc in 32 VGPRs. x staged coalesced to LDS per 32-k chunk.
// Safe when in == agg: block reads exactly the rows it writes, and every
// global read precedes the final __syncthreads().
template <int K, bool RELU>
__global__ __launch_bounds__(256) void k_mm(const float* __restrict__ in, const float* __restrict__ W,
                                            const float* __restrict__ bias, const float* __restrict__ dinv,
                                            float* __restrict__ t_out, float* __restrict__ agg) {
    __shared__ float xs[128 * CHKP];
    const int tid = threadIdx.x;
    const int lane = tid & 63;
    const int wid = tid >> 6;
    const int jhalf = __builtin_amdgcn_readfirstlane(wid & 1);
    const int nloc = (wid >> 1) * 64 + lane;   // 0..127 local node
    const int node0 = blockIdx.x * 128;
    const int node = node0 + nloc;

    float acc[32];
#pragma unroll
    for (int j = 0; j < 32; j++) acc[j] = 0.f;

    const int c4 = tid & 7;     // float4 slot in row (8 per 32-float chunk)
    const int r0 = tid >> 3;    // 0..31

    for (int ko = 0; ko < K; ko += CHK) {
        __syncthreads();
#pragma unroll
        for (int s = 0; s < 4; s++) {
            int r = r0 + s * 32;
            int gn = node0 + r;
            float4 v = make_float4(0.f, 0.f, 0.f, 0.f);
            if (gn < NNODES) v = *(const float4*)&in[(size_t)gn * K + ko + c4 * 4];
            if (RELU) {
                v.x = fmaxf(v.x, 0.f); v.y = fmaxf(v.y, 0.f);
                v.z = fmaxf(v.z, 0.f); v.w = fmaxf(v.w, 0.f);
            }
            float* dp = &xs[r * CHKP + c4 * 4];
            dp[0] = v.x; dp[1] = v.y; dp[2] = v.z; dp[3] = v.w;
        }
        __syncthreads();
        for (int kk = 0; kk < CHK; kk++) {
            float xk = xs[nloc * CHKP + kk];
            const float* Wr = &W[(size_t)(ko + kk) * 64 + jhalf * 32];
#pragma unroll
            for (int j = 0; j < 32; j++) acc[j] = fmaf(xk, Wr[j], acc[j]);
        }
    }

    if (node < NNODES) {
        float dv = dinv[node];
        float dv2 = dv * dv;
        float* tp = &t_out[(size_t)node * 64 + jhalf * 32];
        float* ap = &agg[(size_t)node * 64 + jhalf * 32];
#pragma unroll
        for (int j4 = 0; j4 < 8; j4++) {
            float4 tv = make_float4(acc[j4*4], acc[j4*4+1], acc[j4*4+2], acc[j4*4+3]);
            *(float4*)&tp[j4 * 4] = tv;
            float4 av;
            av.x = bias[jhalf*32 + j4*4 + 0] + tv.x * dv2;
            av.y = bias[jhalf*32 + j4*4 + 1] + tv.y * dv2;
            av.z = bias[jhalf*32 + j4*4 + 2] + tv.z * dv2;
            av.w = bias[jhalf*32 + j4*4 + 3] + tv.w * dv2;
            *(float4*)&ap[j4 * 4] = av;
        }
    }
}

// ---------- aggregation: wave per node, 4 edges in flight, no LDS (max TLP) ----------

__global__ __launch_bounds__(256) void k_agg(const float* __restrict__ t, const int* __restrict__ rowptr,
                                             const int* __restrict__ cnt, const float2* __restrict__ colw,
                                             float* __restrict__ agg) {
    int w = (blockIdx.x * 256 + threadIdx.x) >> 6;   // node
    int lane = threadIdx.x & 63;
    if (w >= NNODES) return;
    int qg = lane >> 4;      // edge-slot group 0..3
    int ql = lane & 15;      // float4 slot within the 64-float row
    int start = rowptr[w];
    int n = cnt[w];
    float4 acc = make_float4(0.f, 0.f, 0.f, 0.f);
    for (int e = qg; e < n; e += 4) {
        float2 p = colw[start + e];
        float4 v = *(const float4*)&t[(size_t)__float_as_int(p.x) * 64 + ql * 4];
        acc.x = fmaf(p.y, v.x, acc.x);
        acc.y = fmaf(p.y, v.y, acc.y);
        acc.z = fmaf(p.y, v.z, acc.z);
        acc.w = fmaf(p.y, v.w, acc.w);
    }
    // reduce the 4 edge-slot groups (lanes l, l^16, l^32, l^48)
    acc.x += __shfl_xor(acc.x, 16); acc.y += __shfl_xor(acc.y, 16);
    acc.z += __shfl_xor(acc.z, 16); acc.w += __shfl_xor(acc.w, 16);
    acc.x += __shfl_xor(acc.x, 32); acc.y += __shfl_xor(acc.y, 32);
    acc.z += __shfl_xor(acc.z, 32); acc.w += __shfl_xor(acc.w, 32);
    if (qg == 0) {
        float4* ap = (float4*)&agg[(size_t)w * 64 + ql * 4];
        float4 o = *ap;
        o.x += acc.x; o.y += acc.y; o.z += acc.z; o.w += acc.w;
        *ap = o;
    }
}

// ---------- pooling + head ----------

#define POOL_CHUNK 256
__global__ __launch_bounds__(256) void k_pool(const float* __restrict__ h, const int* __restrict__ batch,
                                              float* pooled, float* gcnt) {
    int w = (blockIdx.x * 256 + threadIdx.x) >> 6;
    int lane = threadIdx.x & 63;
    int start = w * POOL_CHUNK;
    if (start >= NNODES) return;
    int end = min(start + POOL_CHUNK, NNODES);
    int g = batch[start];
    float acc = 0.f;
    int cn = 0;
    for (int i = start; i < end; i++) {
        int gi = batch[i];
        if (gi != g) {
            atomicAdd(&pooled[g * 64 + lane], acc);
            if (lane == 0) atomicAdd(&gcnt[g], (float)cn);
            g = gi; acc = 0.f; cn = 0;
        }
        acc += fmaxf(h[i * 64 + lane], 0.f);   // relu of layer-3 output
        cn++;
    }
    atomicAdd(&pooled[g * 64 + lane], acc);
    if (lane == 0) atomicAdd(&gcnt[g], (float)cn);
}

__global__ __launch_bounds__(256) void k_final(const float* __restrict__ pooled, const float* __restrict__ gcnt,
                                               const float* __restrict__ Wl, const float* __restrict__ bl,
                                               float* __restrict__ out) {
    int g = (blockIdx.x * 256 + threadIdx.x) >> 6;
    int lane = threadIdx.x & 63;
    if (g >= NGRAPHS) return;
    float c = fmaxf(gcnt[g], 1.f);
    float v = pooled[g * 64 + lane] / c * Wl[lane];
#pragma unroll
    for (int off = 32; off; off >>= 1) v += __shfl_down(v, off);
    if (lane == 0) out[g] = v + bl[0];
}

// ---------- launch ----------

extern "C" void kernel_launch(void* const* d_in, const int* in_sizes, int n_in,
                              void* d_out, int out_size, void* d_ws, size_t ws_size,
                              hipStream_t stream) {
    const float* x  = (const float*)d_in[0];
    const int* ei   = (const int*)d_in[1];
    const int* batch = (const int*)d_in[2];
    const float* W1 = (const float*)d_in[3];
    const float* b1 = (const float*)d_in[4];
    const float* W2 = (const float*)d_in[5];
    const float* b2 = (const float*)d_in[6];
    const float* W3 = (const float*)d_in[7];
    const float* b3 = (const float*)d_in[8];
    const float* Wl = (const float*)d_in[9];
    const float* bl = (const float*)d_in[10];
    const int* src = ei;
    const int* dst = ei + NEDGES;

    char* ws = (char*)d_ws;
    size_t off = 0;
    auto alloc = [&](size_t bytes) { void* p = ws + off; off += (bytes + 255) & ~size_t(255); return p; };
    float*  A      = (float*)alloc((size_t)NNODES * 64 * 4);
    float*  B      = (float*)alloc((size_t)NNODES * 64 * 4);
    float2* colw   = (float2*)alloc((size_t)NEDGES * 8);
    float*  dinv   = (float*)alloc((size_t)NNODES * 4);
    int*    cnt    = (int*)alloc((size_t)NNODES * 4);
    int*    rowptr = (int*)alloc((size_t)NNODES * 4);
    int*    cntmat = (int*)alloc((size_t)NBLKA * NBUCK * 4);
    int*    offmat = (int*)alloc((size_t)NBLKA * NBUCK * 4);
    int*    bbase  = (int*)alloc((NBUCK + 1) * 4);
    float*  pooled = (float*)alloc(NGRAPHS * 64 * 4);
    float*  gcnt   = (float*)alloc(NGRAPHS * 4);
    float*  out    = (float*)d_out;
    int*    ebin   = (int*)A;   // 12.8MB staging aliases A (dead before layer-1 k_mm writes A)

    const int NB_MM = (NNODES + 127) / 128;
    const int NB_W  = ((size_t)NNODES * 64 + 255) / 256;
    const int NB_PL = ((NNODES + POOL_CHUNK - 1) / POOL_CHUNK + 3) / 4;

    k_init<<<(NGRAPHS * HID + 255) / 256, 256, 0, stream>>>(pooled, gcnt);
    k_hist<<<NBLKA, 256, 0, stream>>>(dst, cntmat);
    k_offs<<<1, 256, 0, stream>>>(cntmat, offmat, bbase);
    k_bin<<<NBLKA, 256, 0, stream>>>(src, dst, offmat, ebin);
    k_cnt2<<<NBUCK, 256, 0, stream>>>(ebin, bbase, cnt, rowptr, dinv);
    k_sort<<<NBUCK, 256, 0, stream>>>(ebin, bbase, rowptr, dinv, colw);

    // layer 1: x[N,128] -> A (transform), B (agg init); then aggregate into B
    k_mm<128, false><<<NB_MM, 256, 0, stream>>>(x, W1, b1, dinv, A, B);
    k_agg<<<NB_W, 256, 0, stream>>>(A, rowptr, cnt, colw, B);
    // layer 2 (relu on read)
    k_mm<64, true><<<NB_MM, 256, 0, stream>>>(B, W2, b2, dinv, A, B);
    k_agg<<<NB_W, 256, 0, stream>>>(A, rowptr, cnt, colw, B);
    // layer 3
    k_mm<64, true><<<NB_MM, 256, 0, stream>>>(B, W3, b3, dinv, A, B);
    k_agg<<<NB_W, 256, 0, stream>>>(A, rowptr, cnt, colw, B);

    k_pool<<<NB_PL, 256, 0, stream>>>(B, batch, pooled, gcnt);
    k_final<<<(NGRAPHS * 64 + 255) / 256, 256, 0, stream>>>(pooled, gcnt, Wl, bl, out);
}

// Round 9
// 689.404 us; speedup vs baseline: 7.0326x; 1.0363x over previous
//
#include <hip/hip_runtime.h>

#define NNODES 100000
#define NEDGES 3200000
#define NFEATS 128
#define HID 64
#define NGRAPHS 64
#define NPB 128                              // nodes per bucket
#define NBUCK ((NNODES + NPB - 1) / NPB)     // 782
#define NBLKA 128                            // binning blocks
#define EPB (NEDGES / NBLKA)                 // 25000 edges per binning block

// ---------- setup ----------

__global__ __launch_bounds__(256) void k_init(float* pooled, float* gcnt) {
    int i = blockIdx.x * 256 + threadIdx.x;
    if (i < NGRAPHS * HID) pooled[i] = 0.f;
    if (i < NGRAPHS) gcnt[i] = 0.f;
}

// per-block LDS histogram over buckets -> cntmat[b][j]. zero global atomics.
__global__ __launch_bounds__(256) void k_hist(const int* __restrict__ dst, int* __restrict__ cntmat) {
    __shared__ int h[NBUCK];
    for (int j = threadIdx.x; j < NBUCK; j += 256) h[j] = 0;
    __syncthreads();
    int e0 = blockIdx.x * EPB;
    for (int i = threadIdx.x; i < EPB; i += 256) atomicAdd(&h[dst[e0 + i] >> 7], 1);
    __syncthreads();
    for (int j = threadIdx.x; j < NBUCK; j += 256) cntmat[blockIdx.x * NBUCK + j] = h[j];
}

// single block: bucket totals -> exclusive bases (wave scan) -> per-(block,bucket) offsets
__global__ __launch_bounds__(256) void k_offs(const int* __restrict__ cntmat, int* __restrict__ offmat,
                                              int* __restrict__ bbase) {
    __shared__ int tot[NBUCK];
    __shared__ int bex[NBUCK];
    int tid = threadIdx.x;
    for (int j = tid; j < NBUCK; j += 256) {
        int s = 0;
        for (int b = 0; b < NBLKA; b++) s += cntmat[b * NBUCK + j];
        tot[j] = s;
    }
    __syncthreads();
    if (tid < 64) {   // wave 0: exclusive scan over 782 totals
        int run = 0;
        for (int c = 0; c < NBUCK; c += 64) {
            int j = c + tid;
            int own = (j < NBUCK) ? tot[j] : 0;
            int v = own;
            for (int off = 1; off < 64; off <<= 1) {
                int u = __shfl_up(v, off);
                if (tid >= off) v += u;
            }
            if (j < NBUCK) bex[j] = run + v - own;
            run += __shfl(v, 63);
        }
    }
    __syncthreads();
    for (int j = tid; j < NBUCK; j += 256) {
        int run = bex[j];
        bbase[j] = run;
        for (int b = 0; b < NBLKA; b++) { offmat[b * NBUCK + j] = run; run += cntmat[b * NBUCK + j]; }
    }
    if (tid == 0) bbase[NBUCK] = NEDGES;
}

// place edges into bucket-local regions: LDS cursors, 4B packed record s|dloc<<17
__global__ __launch_bounds__(256) void k_bin(const int* __restrict__ src, const int* __restrict__ dst,
                                             const int* __restrict__ offmat, int* __restrict__ ebin) {
    __shared__ int cur[NBUCK];
    int b = blockIdx.x;
    for (int j = threadIdx.x; j < NBUCK; j += 256) cur[j] = offmat[b * NBUCK + j];
    __syncthreads();
    int e0 = b * EPB;
    for (int i = threadIdx.x; i < EPB; i += 256) {
        int s = src[e0 + i], d = dst[e0 + i];
        int p = atomicAdd(&cur[d >> 7], 1);
        ebin[p] = s | ((d & (NPB - 1)) << 17);
    }
}

// per bucket: LDS per-node histogram + scan -> cnt, rowptr, dinv (no global atomics)
__global__ __launch_bounds__(256) void k_cnt2(const int* __restrict__ ebin, const int* __restrict__ bbase,
                                              int* __restrict__ cnt, int* __restrict__ rowptr,
                                              float* __restrict__ dinv) {
    __shared__ int h[NPB];
    __shared__ int sc[NPB];
    int j = blockIdx.x;
    int tid = threadIdx.x;
    if (tid < NPB) h[tid] = 0;
    __syncthreads();
    int lo = bbase[j], hi = bbase[j + 1];
    for (int i = lo + tid; i < hi; i += 256) atomicAdd(&h[ebin[i] >> 17], 1);
    __syncthreads();
    if (tid < 64) {   // wave 0: exclusive scan over 128 node counts
        int run = 0;
        for (int c = 0; c < NPB; c += 64) {
            int own = h[c + tid];
            int v = own;
            for (int off = 1; off < 64; off <<= 1) {
                int u = __shfl_up(v, off);
                if (tid >= off) v += u;
            }
            sc[c + tid] = run + v - own;
            run += __shfl(v, 63);
        }
    }
    __syncthreads();
    int node = j * NPB + tid;
    if (tid < NPB && node < NNODES) {
        int c = h[tid];
        cnt[node] = c;
        rowptr[node] = lo + sc[tid];
        dinv[node] = rsqrtf((float)(c + 1));   // +1 self loop, always > 0
    }
}

// within-bucket counting sort to per-node CSR order; w computed here.
// Writes confined to the bucket's contiguous ~32KB colw window (L2-resident).
__global__ __launch_bounds__(256) void k_sort(const int* __restrict__ ebin, const int* __restrict__ bbase,
                                              const int* __restrict__ rowptr, const float* __restrict__ dinv,
                                              float2* __restrict__ colw) {
    __shared__ int cur[NPB];
    int j = blockIdx.x;
    int node0 = j * NPB;
    int tid = threadIdx.x;
    if (tid < NPB) cur[tid] = (node0 + tid < NNODES) ? rowptr[node0 + tid] : 0;
    __syncthreads();
    int lo = bbase[j], hi = bbase[j + 1];
    for (int i = lo + tid; i < hi; i += 256) {
        int r = ebin[i];
        int s = r & 0x1FFFF;
        int dloc = r >> 17;
        float w = dinv[s] * dinv[node0 + dloc];
        int p = atomicAdd(&cur[dloc], 1);
        colw[p] = make_float2(__int_as_float(s), w);
    }
}

// ---------- transform (GEMV per node, wave-uniform W -> s_load) ----------

#define CHK 32
#define CHKP 33   // +1 pad: conflict-free stride

// block = 128 nodes x 2 col-halves (256 threads). Thread owns 32 output cols
// of one node; acc in 32 VGPRs. x staged coalesced to LDS per 32-k chunk.
// Safe when in == agg: block reads exactly the rows it writes, and every
// global read precedes the final __syncthreads().
template <int K, bool RELU>
__global__ __launch_bounds__(256) void k_mm(const float* __restrict__ in, const float* __restrict__ W,
                                            const float* __restrict__ bias, const float* __restrict__ dinv,
                                            float* __restrict__ t_out, float* __restrict__ agg) {
    __shared__ float xs[128 * CHKP];
    const int tid = threadIdx.x;
    const int lane = tid & 63;
    const int wid = tid >> 6;
    const int jhalf = __builtin_amdgcn_readfirstlane(wid & 1);
    const int nloc = (wid >> 1) * 64 + lane;   // 0..127 local node
    const int node0 = blockIdx.x * 128;
    const int node = node0 + nloc;

    float acc[32];
#pragma unroll
    for (int j = 0; j < 32; j++) acc[j] = 0.f;

    const int c4 = tid & 7;     // float4 slot in row (8 per 32-float chunk)
    const int r0 = tid >> 3;    // 0..31

    for (int ko = 0; ko < K; ko += CHK) {
        __syncthreads();
#pragma unroll
        for (int s = 0; s < 4; s++) {
            int r = r0 + s * 32;
            int gn = node0 + r;
            float4 v = make_float4(0.f, 0.f, 0.f, 0.f);
            if (gn < NNODES) v = *(const float4*)&in[(size_t)gn * K + ko + c4 * 4];
            if (RELU) {
                v.x = fmaxf(v.x, 0.f); v.y = fmaxf(v.y, 0.f);
                v.z = fmaxf(v.z, 0.f); v.w = fmaxf(v.w, 0.f);
            }
            float* dp = &xs[r * CHKP + c4 * 4];
            dp[0] = v.x; dp[1] = v.y; dp[2] = v.z; dp[3] = v.w;
        }
        __syncthreads();
        for (int kk = 0; kk < CHK; kk++) {
            float xk = xs[nloc * CHKP + kk];
            const float* Wr = &W[(size_t)(ko + kk) * 64 + jhalf * 32];
#pragma unroll
            for (int j = 0; j < 32; j++) acc[j] = fmaf(xk, Wr[j], acc[j]);
        }
    }

    if (node < NNODES) {
        float dv = dinv[node];
        float dv2 = dv * dv;
        float* tp = &t_out[(size_t)node * 64 + jhalf * 32];
        float* ap = &agg[(size_t)node * 64 + jhalf * 32];
#pragma unroll
        for (int j4 = 0; j4 < 8; j4++) {
            float4 tv = make_float4(acc[j4*4], acc[j4*4+1], acc[j4*4+2], acc[j4*4+3]);
            *(float4*)&tp[j4 * 4] = tv;
            float4 av;
            av.x = bias[jhalf*32 + j4*4 + 0] + tv.x * dv2;
            av.y = bias[jhalf*32 + j4*4 + 1] + tv.y * dv2;
            av.z = bias[jhalf*32 + j4*4 + 2] + tv.z * dv2;
            av.w = bias[jhalf*32 + j4*4 + 3] + tv.w * dv2;
            *(float4*)&ap[j4 * 4] = av;
        }
    }
}

// ---------- aggregation: wave per node, 4x unrolled -> 16 edges in flight/wave ----------

__global__ __launch_bounds__(256) void k_agg(const float* __restrict__ t, const int* __restrict__ rowptr,
                                             const int* __restrict__ cnt, const float2* __restrict__ colw,
                                             float* __restrict__ agg) {
    int w = (blockIdx.x * 256 + threadIdx.x) >> 6;   // node
    int lane = threadIdx.x & 63;
    if (w >= NNODES) return;
    int qg = lane >> 4;      // edge-slot group 0..3
    int ql = lane & 15;      // float4 slot within the 64-float row
    int start = rowptr[w];
    int n = cnt[w];
    float4 acc = make_float4(0.f, 0.f, 0.f, 0.f);
    int e = 0;
    // unrolled: 4 independent colw loads then 4 independent 256B gathers in flight
    for (; e + 16 <= n; e += 16) {
        float2 p0 = colw[start + e + qg];
        float2 p1 = colw[start + e + 4 + qg];
        float2 p2 = colw[start + e + 8 + qg];
        float2 p3 = colw[start + e + 12 + qg];
        float4 v0 = *(const float4*)&t[(size_t)__float_as_int(p0.x) * 64 + ql * 4];
        float4 v1 = *(const float4*)&t[(size_t)__float_as_int(p1.x) * 64 + ql * 4];
        float4 v2 = *(const float4*)&t[(size_t)__float_as_int(p2.x) * 64 + ql * 4];
        float4 v3 = *(const float4*)&t[(size_t)__float_as_int(p3.x) * 64 + ql * 4];
        acc.x = fmaf(p0.y, v0.x, acc.x); acc.y = fmaf(p0.y, v0.y, acc.y);
        acc.z = fmaf(p0.y, v0.z, acc.z); acc.w = fmaf(p0.y, v0.w, acc.w);
        acc.x = fmaf(p1.y, v1.x, acc.x); acc.y = fmaf(p1.y, v1.y, acc.y);
        acc.z = fmaf(p1.y, v1.z, acc.z); acc.w = fmaf(p1.y, v1.w, acc.w);
        acc.x = fmaf(p2.y, v2.x, acc.x); acc.y = fmaf(p2.y, v2.y, acc.y);
        acc.z = fmaf(p2.y, v2.z, acc.z); acc.w = fmaf(p2.y, v2.w, acc.w);
        acc.x = fmaf(p3.y, v3.x, acc.x); acc.y = fmaf(p3.y, v3.y, acc.y);
        acc.z = fmaf(p3.y, v3.z, acc.z); acc.w = fmaf(p3.y, v3.w, acc.w);
    }
    for (e += qg; e < n; e += 4) {
        float2 p = colw[start + e];
        float4 v = *(const float4*)&t[(size_t)__float_as_int(p.x) * 64 + ql * 4];
        acc.x = fmaf(p.y, v.x, acc.x);
        acc.y = fmaf(p.y, v.y, acc.y);
        acc.z = fmaf(p.y, v.z, acc.z);
        acc.w = fmaf(p.y, v.w, acc.w);
    }
    // reduce the 4 edge-slot groups (lanes l, l^16, l^32, l^48)
    acc.x += __shfl_xor(acc.x, 16); acc.y += __shfl_xor(acc.y, 16);
    acc.z += __shfl_xor(acc.z, 16); acc.w += __shfl_xor(acc.w, 16);
    acc.x += __shfl_xor(acc.x, 32); acc.y += __shfl_xor(acc.y, 32);
    acc.z += __shfl_xor(acc.z, 32); acc.w += __shfl_xor(acc.w, 32);
    if (qg == 0) {
        float4* ap = (float4*)&agg[(size_t)w * 64 + ql * 4];
        float4 o = *ap;
        o.x += acc.x; o.y += acc.y; o.z += acc.z; o.w += acc.w;
        *ap = o;
    }
}

// ---------- pooling + head ----------

#define POOL_CHUNK 256
__global__ __launch_bounds__(256) void k_pool(const float* __restrict__ h, const int* __restrict__ batch,
                                              float* pooled, float* gcnt) {
    int w = (blockIdx.x * 256 + threadIdx.x) >> 6;
    int lane = threadIdx.x & 63;
    int start = w * POOL_CHUNK;
    if (start >= NNODES) return;
    int end = min(start + POOL_CHUNK, NNODES);
    int g = batch[start];
    float acc = 0.f;
    int cn = 0;
    for (int i = start; i < end; i++) {
        int gi = batch[i];
        if (gi != g) {
            atomicAdd(&pooled[g * 64 + lane], acc);
            if (lane == 0) atomicAdd(&gcnt[g], (float)cn);
            g = gi; acc = 0.f; cn = 0;
        }
        acc += fmaxf(h[i * 64 + lane], 0.f);   // relu of layer-3 output
        cn++;
    }
    atomicAdd(&pooled[g * 64 + lane], acc);
    if (lane == 0) atomicAdd(&gcnt[g], (float)cn);
}

__global__ __launch_bounds__(256) void k_final(const float* __restrict__ pooled, const float* __restrict__ gcnt,
                                               const float* __restrict__ Wl, const float* __restrict__ bl,
                                               float* __restrict__ out) {
    int g = (blockIdx.x * 256 + threadIdx.x) >> 6;
    int lane = threadIdx.x & 63;
    if (g >= NGRAPHS) return;
    float c = fmaxf(gcnt[g], 1.f);
    float v = pooled[g * 64 + lane] / c * Wl[lane];
#pragma unroll
    for (int off = 32; off; off >>= 1) v += __shfl_down(v, off);
    if (lane == 0) out[g] = v + bl[0];
}

// ---------- launch ----------

extern "C" void kernel_launch(void* const* d_in, const int* in_sizes, int n_in,
                              void* d_out, int out_size, void* d_ws, size_t ws_size,
                              hipStream_t stream) {
    const float* x  = (const float*)d_in[0];
    const int* ei   = (const int*)d_in[1];
    const int* batch = (const int*)d_in[2];
    const float* W1 = (const float*)d_in[3];
    const float* b1 = (const float*)d_in[4];
    const float* W2 = (const float*)d_in[5];
    const float* b2 = (const float*)d_in[6];
    const float* W3 = (const float*)d_in[7];
    const float* b3 = (const float*)d_in[8];
    const float* Wl = (const float*)d_in[9];
    const float* bl = (const float*)d_in[10];
    const int* src = ei;
    const int* dst = ei + NEDGES;

    char* ws = (char*)d_ws;
    size_t off = 0;
    auto alloc = [&](size_t bytes) { void* p = ws + off; off += (bytes + 255) & ~size_t(255); return p; };
    float*  A      = (float*)alloc((size_t)NNODES * 64 * 4);
    float*  B      = (float*)alloc((size_t)NNODES * 64 * 4);
    float2* colw   = (float2*)alloc((size_t)NEDGES * 8);
    float*  dinv   = (float*)alloc((size_t)NNODES * 4);
    int*    cnt    = (int*)alloc((size_t)NNODES * 4);
    int*    rowptr = (int*)alloc((size_t)NNODES * 4);
    int*    cntmat = (int*)alloc((size_t)NBLKA * NBUCK * 4);
    int*    offmat = (int*)alloc((size_t)NBLKA * NBUCK * 4);
    int*    bbase  = (int*)alloc((NBUCK + 1) * 4);
    float*  pooled = (float*)alloc(NGRAPHS * 64 * 4);
    float*  gcnt   = (float*)alloc(NGRAPHS * 4);
    float*  out    = (float*)d_out;
    int*    ebin   = (int*)A;   // 12.8MB staging aliases A (dead before layer-1 k_mm writes A)

    const int NB_MM = (NNODES + 127) / 128;
    const int NB_W  = ((size_t)NNODES * 64 + 255) / 256;
    const int NB_PL = ((NNODES + POOL_CHUNK - 1) / POOL_CHUNK + 3) / 4;

    k_init<<<(NGRAPHS * HID + 255) / 256, 256, 0, stream>>>(pooled, gcnt);
    k_hist<<<NBLKA, 256, 0, stream>>>(dst, cntmat);
    k_offs<<<1, 256, 0, stream>>>(cntmat, offmat, bbase);
    k_bin<<<NBLKA, 256, 0, stream>>>(src, dst, offmat, ebin);
    k_cnt2<<<NBUCK, 256, 0, stream>>>(ebin, bbase, cnt, rowptr, dinv);
    k_sort<<<NBUCK, 256, 0, stream>>>(ebin, bbase, rowptr, dinv, colw);

    // layer 1: x[N,128] -> A (transform), B (agg init); then aggregate into B
    k_mm<128, false><<<NB_MM, 256, 0, stream>>>(x, W1, b1, dinv, A, B);
    k_agg<<<NB_W, 256, 0, stream>>>(A, rowptr, cnt, colw, B);
    // layer 2 (relu on read)
    k_mm<64, true><<<NB_MM, 256, 0, stream>>>(B, W2, b2, dinv, A, B);
    k_agg<<<NB_W, 256, 0, stream>>>(A, rowptr, cnt, colw, B);
    // layer 3
    k_mm<64, true><<<NB_MM, 256, 0, stream>>>(B, W3, b3, dinv, A, B);
    k_agg<<<NB_W, 256, 0, stream>>>(A, rowptr, cnt, colw, B);

    k_pool<<<NB_PL, 256, 0, stream>>>(B, batch, pooled, gcnt);
    k_final<<<(NGRAPHS * 64 + 255) / 256, 256, 0, stream>>>(pooled, gcnt, Wl, bl, out);
}

// Round 10
// 551.051 us; speedup vs baseline: 8.7983x; 1.2511x over previous
//
#include <hip/hip_runtime.h>
#include <hip/hip_fp16.h>

#define NNODES 100000
#define NEDGES 3200000
#define NFEATS 128
#define HID 64
#define NGRAPHS 64
#define NPB 128                              // nodes per bucket
#define NBUCK ((NNODES + NPB - 1) / NPB)     // 782
#define NBLKA 128                            // binning blocks
#define EPB (NEDGES / NBLKA)                 // 25000 edges per binning block

// ---------- setup ----------

__global__ __launch_bounds__(256) void k_init(float* pooled, float* gcnt) {
    int i = blockIdx.x * 256 + threadIdx.x;
    if (i < NGRAPHS * HID) pooled[i] = 0.f;
    if (i < NGRAPHS) gcnt[i] = 0.f;
}

// per-block LDS histogram over buckets -> cntmat[b][j]. zero global atomics.
__global__ __launch_bounds__(256) void k_hist(const int* __restrict__ dst, int* __restrict__ cntmat) {
    __shared__ int h[NBUCK];
    for (int j = threadIdx.x; j < NBUCK; j += 256) h[j] = 0;
    __syncthreads();
    int e0 = blockIdx.x * EPB;
    for (int i = threadIdx.x; i < EPB; i += 256) atomicAdd(&h[dst[e0 + i] >> 7], 1);
    __syncthreads();
    for (int j = threadIdx.x; j < NBUCK; j += 256) cntmat[blockIdx.x * NBUCK + j] = h[j];
}

// single block: bucket totals -> exclusive bases (wave scan) -> per-(block,bucket) offsets
__global__ __launch_bounds__(256) void k_offs(const int* __restrict__ cntmat, int* __restrict__ offmat,
                                              int* __restrict__ bbase) {
    __shared__ int tot[NBUCK];
    __shared__ int bex[NBUCK];
    int tid = threadIdx.x;
    for (int j = tid; j < NBUCK; j += 256) {
        int s = 0;
        for (int b = 0; b < NBLKA; b++) s += cntmat[b * NBUCK + j];
        tot[j] = s;
    }
    __syncthreads();
    if (tid < 64) {   // wave 0: exclusive scan over 782 totals
        int run = 0;
        for (int c = 0; c < NBUCK; c += 64) {
            int j = c + tid;
            int own = (j < NBUCK) ? tot[j] : 0;
            int v = own;
            for (int off = 1; off < 64; off <<= 1) {
                int u = __shfl_up(v, off);
                if (tid >= off) v += u;
            }
            if (j < NBUCK) bex[j] = run + v - own;
            run += __shfl(v, 63);
        }
    }
    __syncthreads();
    for (int j = tid; j < NBUCK; j += 256) {
        int run = bex[j];
        bbase[j] = run;
        for (int b = 0; b < NBLKA; b++) { offmat[b * NBUCK + j] = run; run += cntmat[b * NBUCK + j]; }
    }
    if (tid == 0) bbase[NBUCK] = NEDGES;
}

// place edges into bucket-local regions: LDS cursors, 4B packed record s|dloc<<17
__global__ __launch_bounds__(256) void k_bin(const int* __restrict__ src, const int* __restrict__ dst,
                                             const int* __restrict__ offmat, int* __restrict__ ebin) {
    __shared__ int cur[NBUCK];
    int b = blockIdx.x;
    for (int j = threadIdx.x; j < NBUCK; j += 256) cur[j] = offmat[b * NBUCK + j];
    __syncthreads();
    int e0 = b * EPB;
    for (int i = threadIdx.x; i < EPB; i += 256) {
        int s = src[e0 + i], d = dst[e0 + i];
        int p = atomicAdd(&cur[d >> 7], 1);
        ebin[p] = s | ((d & (NPB - 1)) << 17);
    }
}

// per bucket: LDS per-node histogram + scan -> cnt, rowptr, dinv (no global atomics)
__global__ __launch_bounds__(256) void k_cnt2(const int* __restrict__ ebin, const int* __restrict__ bbase,
                                              int* __restrict__ cnt, int* __restrict__ rowptr,
                                              float* __restrict__ dinv) {
    __shared__ int h[NPB];
    __shared__ int sc[NPB];
    int j = blockIdx.x;
    int tid = threadIdx.x;
    if (tid < NPB) h[tid] = 0;
    __syncthreads();
    int lo = bbase[j], hi = bbase[j + 1];
    for (int i = lo + tid; i < hi; i += 256) atomicAdd(&h[ebin[i] >> 17], 1);
    __syncthreads();
    if (tid < 64) {   // wave 0: exclusive scan over 128 node counts
        int run = 0;
        for (int c = 0; c < NPB; c += 64) {
            int own = h[c + tid];
            int v = own;
            for (int off = 1; off < 64; off <<= 1) {
                int u = __shfl_up(v, off);
                if (tid >= off) v += u;
            }
            sc[c + tid] = run + v - own;
            run += __shfl(v, 63);
        }
    }
    __syncthreads();
    int node = j * NPB + tid;
    if (tid < NPB && node < NNODES) {
        int c = h[tid];
        cnt[node] = c;
        rowptr[node] = lo + sc[tid];
        dinv[node] = rsqrtf((float)(c + 1));   // +1 self loop, always > 0
    }
}

// within-bucket counting sort to per-node CSR order; w computed here.
// Writes confined to the bucket's contiguous ~32KB colw window (L2-resident).
__global__ __launch_bounds__(256) void k_sort(const int* __restrict__ ebin, const int* __restrict__ bbase,
                                              const int* __restrict__ rowptr, const float* __restrict__ dinv,
                                              float2* __restrict__ colw) {
    __shared__ int cur[NPB];
    int j = blockIdx.x;
    int node0 = j * NPB;
    int tid = threadIdx.x;
    if (tid < NPB) cur[tid] = (node0 + tid < NNODES) ? rowptr[node0 + tid] : 0;
    __syncthreads();
    int lo = bbase[j], hi = bbase[j + 1];
    for (int i = lo + tid; i < hi; i += 256) {
        int r = ebin[i];
        int s = r & 0x1FFFF;
        int dloc = r >> 17;
        float w = dinv[s] * dinv[node0 + dloc];
        int p = atomicAdd(&cur[dloc], 1);
        colw[p] = make_float2(__int_as_float(s), w);
    }
}

// ---------- transform (GEMV per node, wave-uniform W -> s_load) ----------

#define CHK 32
#define CHKP 33   // +1 pad: conflict-free stride

// block = 128 nodes x 2 col-halves (256 threads). Thread owns 32 output cols
// of one node; acc in 32 VGPRs. x staged coalesced to LDS per 32-k chunk.
// t_out written fp16 (gather buffer); agg stays fp32.
// Safe when in == agg: block reads exactly the rows it writes, and every
// global read precedes the final __syncthreads().
template <int K, bool RELU>
__global__ __launch_bounds__(256) void k_mm(const float* __restrict__ in, const float* __restrict__ W,
                                            const float* __restrict__ bias, const float* __restrict__ dinv,
                                            __half* __restrict__ t_out, float* __restrict__ agg) {
    __shared__ float xs[128 * CHKP];
    const int tid = threadIdx.x;
    const int lane = tid & 63;
    const int wid = tid >> 6;
    const int jhalf = __builtin_amdgcn_readfirstlane(wid & 1);
    const int nloc = (wid >> 1) * 64 + lane;   // 0..127 local node
    const int node0 = blockIdx.x * 128;
    const int node = node0 + nloc;

    float acc[32];
#pragma unroll
    for (int j = 0; j < 32; j++) acc[j] = 0.f;

    const int c4 = tid & 7;     // float4 slot in row (8 per 32-float chunk)
    const int r0 = tid >> 3;    // 0..31

    for (int ko = 0; ko < K; ko += CHK) {
        __syncthreads();
#pragma unroll
        for (int s = 0; s < 4; s++) {
            int r = r0 + s * 32;
            int gn = node0 + r;
            float4 v = make_float4(0.f, 0.f, 0.f, 0.f);
            if (gn < NNODES) v = *(const float4*)&in[(size_t)gn * K + ko + c4 * 4];
            if (RELU) {
                v.x = fmaxf(v.x, 0.f); v.y = fmaxf(v.y, 0.f);
                v.z = fmaxf(v.z, 0.f); v.w = fmaxf(v.w, 0.f);
            }
            float* dp = &xs[r * CHKP + c4 * 4];
            dp[0] = v.x; dp[1] = v.y; dp[2] = v.z; dp[3] = v.w;
        }
        __syncthreads();
        for (int kk = 0; kk < CHK; kk++) {
            float xk = xs[nloc * CHKP + kk];
            const float* Wr = &W[(size_t)(ko + kk) * 64 + jhalf * 32];
#pragma unroll
            for (int j = 0; j < 32; j++) acc[j] = fmaf(xk, Wr[j], acc[j]);
        }
    }

    if (node < NNODES) {
        float dv = dinv[node];
        float dv2 = dv * dv;
        __half* tp = &t_out[(size_t)node * 64 + jhalf * 32];
        float* ap = &agg[(size_t)node * 64 + jhalf * 32];
#pragma unroll
        for (int j4 = 0; j4 < 8; j4++) {
            float4 tv = make_float4(acc[j4*4], acc[j4*4+1], acc[j4*4+2], acc[j4*4+3]);
            union { __half2 h[2]; float2 f; } u;
            u.h[0] = __floats2half2_rn(tv.x, tv.y);
            u.h[1] = __floats2half2_rn(tv.z, tv.w);
            *(float2*)&tp[j4 * 4] = u.f;           // 8B packed fp16 store
            float4 av;
            av.x = bias[jhalf*32 + j4*4 + 0] + tv.x * dv2;
            av.y = bias[jhalf*32 + j4*4 + 1] + tv.y * dv2;
            av.z = bias[jhalf*32 + j4*4 + 2] + tv.z * dv2;
            av.w = bias[jhalf*32 + j4*4 + 3] + tv.w * dv2;
            *(float4*)&ap[j4 * 4] = av;
        }
    }
}

// ---------- aggregation: wave per node, 4x unrolled, fp16 rows (128B) ----------

__device__ __forceinline__ void agg_edge(const __half* t, float2 p, int ql, float4& acc) {
    float2 raw = *(const float2*)&t[(size_t)__float_as_int(p.x) * 64 + ql * 4];  // 8B = 4 halves
    const __half2* hp = (const __half2*)&raw;
    float2 f0 = __half22float2(hp[0]);
    float2 f1 = __half22float2(hp[1]);
    acc.x = fmaf(p.y, f0.x, acc.x);
    acc.y = fmaf(p.y, f0.y, acc.y);
    acc.z = fmaf(p.y, f1.x, acc.z);
    acc.w = fmaf(p.y, f1.y, acc.w);
}

__global__ __launch_bounds__(256) void k_agg(const __half* __restrict__ t, const int* __restrict__ rowptr,
                                             const int* __restrict__ cnt, const float2* __restrict__ colw,
                                             float* __restrict__ agg) {
    int w = (blockIdx.x * 256 + threadIdx.x) >> 6;   // node
    int lane = threadIdx.x & 63;
    if (w >= NNODES) return;
    int qg = lane >> 4;      // edge-slot group 0..3
    int ql = lane & 15;      // half4 slot within the 64-half row
    int start = rowptr[w];
    int n = cnt[w];
    float4 acc = make_float4(0.f, 0.f, 0.f, 0.f);
    int e = 0;
    // unrolled: 4 independent colw loads then 4 independent 128B row gathers in flight
    for (; e + 16 <= n; e += 16) {
        float2 p0 = colw[start + e + qg];
        float2 p1 = colw[start + e + 4 + qg];
        float2 p2 = colw[start + e + 8 + qg];
        float2 p3 = colw[start + e + 12 + qg];
        agg_edge(t, p0, ql, acc);
        agg_edge(t, p1, ql, acc);
        agg_edge(t, p2, ql, acc);
        agg_edge(t, p3, ql, acc);
    }
    for (e += qg; e < n; e += 4) {
        agg_edge(t, colw[start + e], ql, acc);
    }
    // reduce the 4 edge-slot groups (lanes l, l^16, l^32, l^48)
    acc.x += __shfl_xor(acc.x, 16); acc.y += __shfl_xor(acc.y, 16);
    acc.z += __shfl_xor(acc.z, 16); acc.w += __shfl_xor(acc.w, 16);
    acc.x += __shfl_xor(acc.x, 32); acc.y += __shfl_xor(acc.y, 32);
    acc.z += __shfl_xor(acc.z, 32); acc.w += __shfl_xor(acc.w, 32);
    if (qg == 0) {
        float4* ap = (float4*)&agg[(size_t)w * 64 + ql * 4];
        float4 o = *ap;
        o.x += acc.x; o.y += acc.y; o.z += acc.z; o.w += acc.w;
        *ap = o;
    }
}

// ---------- pooling + head ----------

#define POOL_CHUNK 256
__global__ __launch_bounds__(256) void k_pool(const float* __restrict__ h, const int* __restrict__ batch,
                                              float* pooled, float* gcnt) {
    int w = (blockIdx.x * 256 + threadIdx.x) >> 6;
    int lane = threadIdx.x & 63;
    int start = w * POOL_CHUNK;
    if (start >= NNODES) return;
    int end = min(start + POOL_CHUNK, NNODES);
    int g = batch[start];
    float acc = 0.f;
    int cn = 0;
    for (int i = start; i < end; i++) {
        int gi = batch[i];
        if (gi != g) {
            atomicAdd(&pooled[g * 64 + lane], acc);
            if (lane == 0) atomicAdd(&gcnt[g], (float)cn);
            g = gi; acc = 0.f; cn = 0;
        }
        acc += fmaxf(h[i * 64 + lane], 0.f);   // relu of layer-3 output
        cn++;
    }
    atomicAdd(&pooled[g * 64 + lane], acc);
    if (lane == 0) atomicAdd(&gcnt[g], (float)cn);
}

__global__ __launch_bounds__(256) void k_final(const float* __restrict__ pooled, const float* __restrict__ gcnt,
                                               const float* __restrict__ Wl, const float* __restrict__ bl,
                                               float* __restrict__ out) {
    int g = (blockIdx.x * 256 + threadIdx.x) >> 6;
    int lane = threadIdx.x & 63;
    if (g >= NGRAPHS) return;
    float c = fmaxf(gcnt[g], 1.f);
    float v = pooled[g * 64 + lane] / c * Wl[lane];
#pragma unroll
    for (int off = 32; off; off >>= 1) v += __shfl_down(v, off);
    if (lane == 0) out[g] = v + bl[0];
}

// ---------- launch ----------

extern "C" void kernel_launch(void* const* d_in, const int* in_sizes, int n_in,
                              void* d_out, int out_size, void* d_ws, size_t ws_size,
                              hipStream_t stream) {
    const float* x  = (const float*)d_in[0];
    const int* ei   = (const int*)d_in[1];
    const int* batch = (const int*)d_in[2];
    const float* W1 = (const float*)d_in[3];
    const float* b1 = (const float*)d_in[4];
    const float* W2 = (const float*)d_in[5];
    const float* b2 = (const float*)d_in[6];
    const float* W3 = (const float*)d_in[7];
    const float* b3 = (const float*)d_in[8];
    const float* Wl = (const float*)d_in[9];
    const float* bl = (const float*)d_in[10];
    const int* src = ei;
    const int* dst = ei + NEDGES;

    char* ws = (char*)d_ws;
    size_t off = 0;
    auto alloc = [&](size_t bytes) { void* p = ws + off; off += (bytes + 255) & ~size_t(255); return p; };
    __half* A      = (__half*)alloc((size_t)NNODES * 64 * 2);   // fp16 gather buffer (12.8MB)
    float*  B      = (float*)alloc((size_t)NNODES * 64 * 4);
    float2* colw   = (float2*)alloc((size_t)NEDGES * 8);
    float*  dinv   = (float*)alloc((size_t)NNODES * 4);
    int*    cnt    = (int*)alloc((size_t)NNODES * 4);
    int*    rowptr = (int*)alloc((size_t)NNODES * 4);
    int*    cntmat = (int*)alloc((size_t)NBLKA * NBUCK * 4);
    int*    offmat = (int*)alloc((size_t)NBLKA * NBUCK * 4);
    int*    bbase  = (int*)alloc((NBUCK + 1) * 4);
    float*  pooled = (float*)alloc(NGRAPHS * 64 * 4);
    float*  gcnt   = (float*)alloc(NGRAPHS * 4);
    float*  out    = (float*)d_out;
    int*    ebin   = (int*)A;   // 12.8MB staging aliases A (dead before layer-1 k_mm writes A)

    const int NB_MM = (NNODES + 127) / 128;
    const int NB_W  = ((size_t)NNODES * 64 + 255) / 256;
    const int NB_PL = ((NNODES + POOL_CHUNK - 1) / POOL_CHUNK + 3) / 4;

    k_init<<<(NGRAPHS * HID + 255) / 256, 256, 0, stream>>>(pooled, gcnt);
    k_hist<<<NBLKA, 256, 0, stream>>>(dst, cntmat);
    k_offs<<<1, 256, 0, stream>>>(cntmat, offmat, bbase);
    k_bin<<<NBLKA, 256, 0, stream>>>(src, dst, offmat, ebin);
    k_cnt2<<<NBUCK, 256, 0, stream>>>(ebin, bbase, cnt, rowptr, dinv);
    k_sort<<<NBUCK, 256, 0, stream>>>(ebin, bbase, rowptr, dinv, colw);

    // layer 1: x[N,128] -> A (transform, fp16), B (agg init, fp32); aggregate into B
    k_mm<128, false><<<NB_MM, 256, 0, stream>>>(x, W1, b1, dinv, A, B);
    k_agg<<<NB_W, 256, 0, stream>>>(A, rowptr, cnt, colw, B);
    // layer 2 (relu on read)
    k_mm<64, true><<<NB_MM, 256, 0, stream>>>(B, W2, b2, dinv, A, B);
    k_agg<<<NB_W, 256, 0, stream>>>(A, rowptr, cnt, colw, B);
    // layer 3
    k_mm<64, true><<<NB_MM, 256, 0, stream>>>(B, W3, b3, dinv, A, B);
    k_agg<<<NB_W, 256, 0, stream>>>(A, rowptr, cnt, colw, B);

    k_pool<<<NB_PL, 256, 0, stream>>>(B, batch, pooled, gcnt);
    k_final<<<(NGRAPHS * 64 + 255) / 256, 256, 0, stream>>>(pooled, gcnt, Wl, bl, out);
}

// Round 11
// 485.475 us; speedup vs baseline: 9.9867x; 1.1351x over previous
//
#include <hip/hip_runtime.h>
#include <hip/hip_fp16.h>

#define NNODES 100000
#define NEDGES 3200000
#define NFEATS 128
#define HID 64
#define NGRAPHS 64
#define NPB 128                              // nodes per bucket
#define NBUCK ((NNODES + NPB - 1) / NPB)     // 782
#define NBLKA 128                            // binning blocks
#define EPB (NEDGES / NBLKA)                 // 25000 edges per binning block

// ---------- setup ----------

__global__ __launch_bounds__(256) void k_init(float* pooled, float* gcnt) {
    int i = blockIdx.x * 256 + threadIdx.x;
    if (i < NGRAPHS * HID) pooled[i] = 0.f;
    if (i < NGRAPHS) gcnt[i] = 0.f;
}

// per-block LDS histogram over buckets -> cntmat[b][j]. zero global atomics.
__global__ __launch_bounds__(256) void k_hist(const int* __restrict__ dst, int* __restrict__ cntmat) {
    __shared__ int h[NBUCK];
    for (int j = threadIdx.x; j < NBUCK; j += 256) h[j] = 0;
    __syncthreads();
    int e0 = blockIdx.x * EPB;
    for (int i = threadIdx.x; i < EPB; i += 256) atomicAdd(&h[dst[e0 + i] >> 7], 1);
    __syncthreads();
    for (int j = threadIdx.x; j < NBUCK; j += 256) cntmat[blockIdx.x * NBUCK + j] = h[j];
}

// single block: bucket totals -> exclusive bases (wave scan) -> per-(block,bucket) offsets
__global__ __launch_bounds__(256) void k_offs(const int* __restrict__ cntmat, int* __restrict__ offmat,
                                              int* __restrict__ bbase) {
    __shared__ int tot[NBUCK];
    __shared__ int bex[NBUCK];
    int tid = threadIdx.x;
    for (int j = tid; j < NBUCK; j += 256) {
        int s = 0;
        for (int b = 0; b < NBLKA; b++) s += cntmat[b * NBUCK + j];
        tot[j] = s;
    }
    __syncthreads();
    if (tid < 64) {   // wave 0: exclusive scan over 782 totals
        int run = 0;
        for (int c = 0; c < NBUCK; c += 64) {
            int j = c + tid;
            int own = (j < NBUCK) ? tot[j] : 0;
            int v = own;
            for (int off = 1; off < 64; off <<= 1) {
                int u = __shfl_up(v, off);
                if (tid >= off) v += u;
            }
            if (j < NBUCK) bex[j] = run + v - own;
            run += __shfl(v, 63);
        }
    }
    __syncthreads();
    for (int j = tid; j < NBUCK; j += 256) {
        int run = bex[j];
        bbase[j] = run;
        for (int b = 0; b < NBLKA; b++) { offmat[b * NBUCK + j] = run; run += cntmat[b * NBUCK + j]; }
    }
    if (tid == 0) bbase[NBUCK] = NEDGES;
}

// place edges into bucket-local regions: LDS cursors, 4B packed record s|dloc<<17
__global__ __launch_bounds__(256) void k_bin(const int* __restrict__ src, const int* __restrict__ dst,
                                             const int* __restrict__ offmat, int* __restrict__ ebin) {
    __shared__ int cur[NBUCK];
    int b = blockIdx.x;
    for (int j = threadIdx.x; j < NBUCK; j += 256) cur[j] = offmat[b * NBUCK + j];
    __syncthreads();
    int e0 = b * EPB;
    for (int i = threadIdx.x; i < EPB; i += 256) {
        int s = src[e0 + i], d = dst[e0 + i];
        int p = atomicAdd(&cur[d >> 7], 1);
        ebin[p] = s | ((d & (NPB - 1)) << 17);
    }
}

// per bucket: LDS per-node histogram + scan -> cnt, rowptr, dinv (no global atomics)
__global__ __launch_bounds__(256) void k_cnt2(const int* __restrict__ ebin, const int* __restrict__ bbase,
                                              int* __restrict__ cnt, int* __restrict__ rowptr,
                                              float* __restrict__ dinv) {
    __shared__ int h[NPB];
    __shared__ int sc[NPB];
    int j = blockIdx.x;
    int tid = threadIdx.x;
    if (tid < NPB) h[tid] = 0;
    __syncthreads();
    int lo = bbase[j], hi = bbase[j + 1];
    for (int i = lo + tid; i < hi; i += 256) atomicAdd(&h[ebin[i] >> 17], 1);
    __syncthreads();
    if (tid < 64) {   // wave 0: exclusive scan over 128 node counts
        int run = 0;
        for (int c = 0; c < NPB; c += 64) {
            int own = h[c + tid];
            int v = own;
            for (int off = 1; off < 64; off <<= 1) {
                int u = __shfl_up(v, off);
                if (tid >= off) v += u;
            }
            sc[c + tid] = run + v - own;
            run += __shfl(v, 63);
        }
    }
    __syncthreads();
    int node = j * NPB + tid;
    if (tid < NPB && node < NNODES) {
        int c = h[tid];
        cnt[node] = c;
        rowptr[node] = lo + sc[tid];
        dinv[node] = rsqrtf((float)(c + 1));   // +1 self loop, always > 0
    }
}

// within-bucket counting sort to per-node CSR order; w computed here.
// Writes confined to the bucket's contiguous ~32KB colw window (L2-resident).
__global__ __launch_bounds__(256) void k_sort(const int* __restrict__ ebin, const int* __restrict__ bbase,
                                              const int* __restrict__ rowptr, const float* __restrict__ dinv,
                                              float2* __restrict__ colw) {
    __shared__ int cur[NPB];
    int j = blockIdx.x;
    int node0 = j * NPB;
    int tid = threadIdx.x;
    if (tid < NPB) cur[tid] = (node0 + tid < NNODES) ? rowptr[node0 + tid] : 0;
    __syncthreads();
    int lo = bbase[j], hi = bbase[j + 1];
    for (int i = lo + tid; i < hi; i += 256) {
        int r = ebin[i];
        int s = r & 0x1FFFF;
        int dloc = r >> 17;
        float w = dinv[s] * dinv[node0 + dloc];
        int p = atomicAdd(&cur[dloc], 1);
        colw[p] = make_float2(__int_as_float(s), w);
    }
}

// ---------- transform (GEMV per node, wave-uniform W -> s_load) ----------

#define CHK 32
#define CHKP 33   // +1 pad: conflict-free stride

// block = 128 nodes x 2 col-halves (256 threads). Thread owns 32 output cols
// of one node; acc in 32 VGPRs. x staged coalesced to LDS per 32-k chunk.
// t_out written fp16 (gather buffer); agg stays fp32.
// Safe when in == agg: block reads exactly the rows it writes, and every
// global read precedes the final __syncthreads().
template <int K, bool RELU>
__global__ __launch_bounds__(256) void k_mm(const float* __restrict__ in, const float* __restrict__ W,
                                            const float* __restrict__ bias, const float* __restrict__ dinv,
                                            __half* __restrict__ t_out, float* __restrict__ agg) {
    __shared__ float xs[128 * CHKP];
    const int tid = threadIdx.x;
    const int lane = tid & 63;
    const int wid = tid >> 6;
    const int jhalf = __builtin_amdgcn_readfirstlane(wid & 1);
    const int nloc = (wid >> 1) * 64 + lane;   // 0..127 local node
    const int node0 = blockIdx.x * 128;
    const int node = node0 + nloc;

    float acc[32];
#pragma unroll
    for (int j = 0; j < 32; j++) acc[j] = 0.f;

    const int c4 = tid & 7;     // float4 slot in row (8 per 32-float chunk)
    const int r0 = tid >> 3;    // 0..31

    for (int ko = 0; ko < K; ko += CHK) {
        __syncthreads();
#pragma unroll
        for (int s = 0; s < 4; s++) {
            int r = r0 + s * 32;
            int gn = node0 + r;
            float4 v = make_float4(0.f, 0.f, 0.f, 0.f);
            if (gn < NNODES) v = *(const float4*)&in[(size_t)gn * K + ko + c4 * 4];
            if (RELU) {
                v.x = fmaxf(v.x, 0.f); v.y = fmaxf(v.y, 0.f);
                v.z = fmaxf(v.z, 0.f); v.w = fmaxf(v.w, 0.f);
            }
            float* dp = &xs[r * CHKP + c4 * 4];
            dp[0] = v.x; dp[1] = v.y; dp[2] = v.z; dp[3] = v.w;
        }
        __syncthreads();
        for (int kk = 0; kk < CHK; kk++) {
            float xk = xs[nloc * CHKP + kk];
            const float* Wr = &W[(size_t)(ko + kk) * 64 + jhalf * 32];
#pragma unroll
            for (int j = 0; j < 32; j++) acc[j] = fmaf(xk, Wr[j], acc[j]);
        }
    }

    if (node < NNODES) {
        float dv = dinv[node];
        float dv2 = dv * dv;
        __half* tp = &t_out[(size_t)node * 64 + jhalf * 32];
        float* ap = &agg[(size_t)node * 64 + jhalf * 32];
#pragma unroll
        for (int j4 = 0; j4 < 8; j4++) {
            float4 tv = make_float4(acc[j4*4], acc[j4*4+1], acc[j4*4+2], acc[j4*4+3]);
            union { __half2 h[2]; float2 f; } u;
            u.h[0] = __floats2half2_rn(tv.x, tv.y);
            u.h[1] = __floats2half2_rn(tv.z, tv.w);
            *(float2*)&tp[j4 * 4] = u.f;           // 8B packed fp16 store
            float4 av;
            av.x = bias[jhalf*32 + j4*4 + 0] + tv.x * dv2;
            av.y = bias[jhalf*32 + j4*4 + 1] + tv.y * dv2;
            av.z = bias[jhalf*32 + j4*4 + 2] + tv.z * dv2;
            av.w = bias[jhalf*32 + j4*4 + 3] + tv.w * dv2;
            *(float4*)&ap[j4 * 4] = av;
        }
    }
}

// ---------- aggregation: wave per node, 4x unrolled, fp16 rows (128B) ----------

__device__ __forceinline__ void agg_edge(const __half* t, float2 p, int ql, float4& acc) {
    float2 raw = *(const float2*)&t[(size_t)__float_as_int(p.x) * 64 + ql * 4];  // 8B = 4 halves
    const __half2* hp = (const __half2*)&raw;
    float2 f0 = __half22float2(hp[0]);
    float2 f1 = __half22float2(hp[1]);
    acc.x = fmaf(p.y, f0.x, acc.x);
    acc.y = fmaf(p.y, f0.y, acc.y);
    acc.z = fmaf(p.y, f1.x, acc.z);
    acc.w = fmaf(p.y, f1.y, acc.w);
}

__global__ __launch_bounds__(256) void k_agg(const __half* __restrict__ t, const int* __restrict__ rowptr,
                                             const int* __restrict__ cnt, const float2* __restrict__ colw,
                                             float* __restrict__ agg) {
    int w = (blockIdx.x * 256 + threadIdx.x) >> 6;   // node
    int lane = threadIdx.x & 63;
    if (w >= NNODES) return;
    int qg = lane >> 4;      // edge-slot group 0..3
    int ql = lane & 15;      // half4 slot within the 64-half row
    int start = rowptr[w];
    int n = cnt[w];
    float4 acc = make_float4(0.f, 0.f, 0.f, 0.f);
    int e = 0;
    // unrolled: 4 independent colw loads then 4 independent 128B row gathers in flight
    for (; e + 16 <= n; e += 16) {
        float2 p0 = colw[start + e + qg];
        float2 p1 = colw[start + e + 4 + qg];
        float2 p2 = colw[start + e + 8 + qg];
        float2 p3 = colw[start + e + 12 + qg];
        agg_edge(t, p0, ql, acc);
        agg_edge(t, p1, ql, acc);
        agg_edge(t, p2, ql, acc);
        agg_edge(t, p3, ql, acc);
    }
    for (e += qg; e < n; e += 4) {
        agg_edge(t, colw[start + e], ql, acc);
    }
    // reduce the 4 edge-slot groups (lanes l, l^16, l^32, l^48)
    acc.x += __shfl_xor(acc.x, 16); acc.y += __shfl_xor(acc.y, 16);
    acc.z += __shfl_xor(acc.z, 16); acc.w += __shfl_xor(acc.w, 16);
    acc.x += __shfl_xor(acc.x, 32); acc.y += __shfl_xor(acc.y, 32);
    acc.z += __shfl_xor(acc.z, 32); acc.w += __shfl_xor(acc.w, 32);
    if (qg == 0) {
        float4* ap = (float4*)&agg[(size_t)w * 64 + ql * 4];
        float4 o = *ap;
        o.x += acc.x; o.y += acc.y; o.z += acc.z; o.w += acc.w;
        *ap = o;
    }
}

// ---------- pooling + head ----------

// batch is SORTED: segmented reduction. Wave per 32-node chunk (3125 waves),
// 4-deep unrolled row loads for MLP; flush one atomicAdd per segment boundary.
#define POOL_CHUNK 32
__global__ __launch_bounds__(256) void k_pool(const float* __restrict__ h, const int* __restrict__ batch,
                                              float* pooled, float* gcnt) {
    int w = (blockIdx.x * 256 + threadIdx.x) >> 6;
    int lane = threadIdx.x & 63;
    int start = w * POOL_CHUNK;
    if (start >= NNODES) return;
    int end = min(start + POOL_CHUNK, NNODES);
    int g = batch[start];
    float acc = 0.f;
    float cn = 0.f;
    int i = start;
    for (; i + 4 <= end; i += 4) {
        int b0 = batch[i], b1 = batch[i + 1], b2 = batch[i + 2], b3 = batch[i + 3];
        float v0 = h[(size_t)i * 64 + lane];
        float v1 = h[(size_t)(i + 1) * 64 + lane];
        float v2 = h[(size_t)(i + 2) * 64 + lane];
        float v3 = h[(size_t)(i + 3) * 64 + lane];
        if (b0 != g) {
            atomicAdd(&pooled[g * 64 + lane], acc);
            if (lane == 0) atomicAdd(&gcnt[g], cn);
            g = b0; acc = 0.f; cn = 0.f;
        }
        acc += fmaxf(v0, 0.f); cn += 1.f;
        if (b1 != g) {
            atomicAdd(&pooled[g * 64 + lane], acc);
            if (lane == 0) atomicAdd(&gcnt[g], cn);
            g = b1; acc = 0.f; cn = 0.f;
        }
        acc += fmaxf(v1, 0.f); cn += 1.f;
        if (b2 != g) {
            atomicAdd(&pooled[g * 64 + lane], acc);
            if (lane == 0) atomicAdd(&gcnt[g], cn);
            g = b2; acc = 0.f; cn = 0.f;
        }
        acc += fmaxf(v2, 0.f); cn += 1.f;
        if (b3 != g) {
            atomicAdd(&pooled[g * 64 + lane], acc);
            if (lane == 0) atomicAdd(&gcnt[g], cn);
            g = b3; acc = 0.f; cn = 0.f;
        }
        acc += fmaxf(v3, 0.f); cn += 1.f;
    }
    for (; i < end; i++) {
        int gi = batch[i];
        if (gi != g) {
            atomicAdd(&pooled[g * 64 + lane], acc);
            if (lane == 0) atomicAdd(&gcnt[g], cn);
            g = gi; acc = 0.f; cn = 0.f;
        }
        acc += fmaxf(h[(size_t)i * 64 + lane], 0.f);
        cn += 1.f;
    }
    atomicAdd(&pooled[g * 64 + lane], acc);
    if (lane == 0) atomicAdd(&gcnt[g], cn);
}

__global__ __launch_bounds__(256) void k_final(const float* __restrict__ pooled, const float* __restrict__ gcnt,
                                               const float* __restrict__ Wl, const float* __restrict__ bl,
                                               float* __restrict__ out) {
    int g = (blockIdx.x * 256 + threadIdx.x) >> 6;
    int lane = threadIdx.x & 63;
    if (g >= NGRAPHS) return;
    float c = fmaxf(gcnt[g], 1.f);
    float v = pooled[g * 64 + lane] / c * Wl[lane];
#pragma unroll
    for (int off = 32; off; off >>= 1) v += __shfl_down(v, off);
    if (lane == 0) out[g] = v + bl[0];
}

// ---------- launch ----------

extern "C" void kernel_launch(void* const* d_in, const int* in_sizes, int n_in,
                              void* d_out, int out_size, void* d_ws, size_t ws_size,
                              hipStream_t stream) {
    const float* x  = (const float*)d_in[0];
    const int* ei   = (const int*)d_in[1];
    const int* batch = (const int*)d_in[2];
    const float* W1 = (const float*)d_in[3];
    const float* b1 = (const float*)d_in[4];
    const float* W2 = (const float*)d_in[5];
    const float* b2 = (const float*)d_in[6];
    const float* W3 = (const float*)d_in[7];
    const float* b3 = (const float*)d_in[8];
    const float* Wl = (const float*)d_in[9];
    const float* bl = (const float*)d_in[10];
    const int* src = ei;
    const int* dst = ei + NEDGES;

    char* ws = (char*)d_ws;
    size_t off = 0;
    auto alloc = [&](size_t bytes) { void* p = ws + off; off += (bytes + 255) & ~size_t(255); return p; };
    __half* A      = (__half*)alloc((size_t)NNODES * 64 * 2);   // fp16 gather buffer (12.8MB)
    float*  B      = (float*)alloc((size_t)NNODES * 64 * 4);
    float2* colw   = (float2*)alloc((size_t)NEDGES * 8);
    float*  dinv   = (float*)alloc((size_t)NNODES * 4);
    int*    cnt    = (int*)alloc((size_t)NNODES * 4);
    int*    rowptr = (int*)alloc((size_t)NNODES * 4);
    int*    cntmat = (int*)alloc((size_t)NBLKA * NBUCK * 4);
    int*    offmat = (int*)alloc((size_t)NBLKA * NBUCK * 4);
    int*    bbase  = (int*)alloc((NBUCK + 1) * 4);
    float*  pooled = (float*)alloc(NGRAPHS * 64 * 4);
    float*  gcnt   = (float*)alloc(NGRAPHS * 4);
    float*  out    = (float*)d_out;
    int*    ebin   = (int*)A;   // 12.8MB staging aliases A (dead before layer-1 k_mm writes A)

    const int NB_MM = (NNODES + 127) / 128;
    const int NB_W  = ((size_t)NNODES * 64 + 255) / 256;
    const int NB_PL = ((NNODES + POOL_CHUNK - 1) / POOL_CHUNK + 3) / 4;

    k_init<<<(NGRAPHS * HID + 255) / 256, 256, 0, stream>>>(pooled, gcnt);
    k_hist<<<NBLKA, 256, 0, stream>>>(dst, cntmat);
    k_offs<<<1, 256, 0, stream>>>(cntmat, offmat, bbase);
    k_bin<<<NBLKA, 256, 0, stream>>>(src, dst, offmat, ebin);
    k_cnt2<<<NBUCK, 256, 0, stream>>>(ebin, bbase, cnt, rowptr, dinv);
    k_sort<<<NBUCK, 256, 0, stream>>>(ebin, bbase, rowptr, dinv, colw);

    // layer 1: x[N,128] -> A (transform, fp16), B (agg init, fp32); aggregate into B
    k_mm<128, false><<<NB_MM, 256, 0, stream>>>(x, W1, b1, dinv, A, B);
    k_agg<<<NB_W, 256, 0, stream>>>(A, rowptr, cnt, colw, B);
    // layer 2 (relu on read)
    k_mm<64, true><<<NB_MM, 256, 0, stream>>>(B, W2, b2, dinv, A, B);
    k_agg<<<NB_W, 256, 0, stream>>>(A, rowptr, cnt, colw, B);
    // layer 3
    k_mm<64, true><<<NB_MM, 256, 0, stream>>>(B, W3, b3, dinv, A, B);
    k_agg<<<NB_W, 256, 0, stream>>>(A, rowptr, cnt, colw, B);

    k_pool<<<NB_PL, 256, 0, stream>>>(B, batch, pooled, gcnt);
    k_final<<<(NGRAPHS * 64 + 255) / 256, 256, 0, stream>>>(pooled, gcnt, Wl, bl, out);
}

// Round 12
// 419.251 us; speedup vs baseline: 11.5642x; 1.1580x over previous
//
#include <hip/hip_runtime.h>
#include <hip/hip_fp16.h>

#define NNODES 100000
#define NEDGES 3200000
#define NFEATS 128
#define HID 64
#define NGRAPHS 64
#define NPB 128                              // nodes per bucket
#define NBUCK ((NNODES + NPB - 1) / NPB)     // 782
#define NBLKA 128                            // binning blocks
#define EPB (NEDGES / NBLKA)                 // 25000 edges per binning block

// ---------- setup ----------

__global__ __launch_bounds__(256) void k_init(float* pooled, float* gcnt) {
    int i = blockIdx.x * 256 + threadIdx.x;
    if (i < NGRAPHS * HID) pooled[i] = 0.f;
    if (i < NGRAPHS) gcnt[i] = 0.f;
}

// per-block LDS histogram over buckets -> cntmat[b][j]. zero global atomics.
__global__ __launch_bounds__(256) void k_hist(const int* __restrict__ dst, int* __restrict__ cntmat) {
    __shared__ int h[NBUCK];
    for (int j = threadIdx.x; j < NBUCK; j += 256) h[j] = 0;
    __syncthreads();
    int e0 = blockIdx.x * EPB;
    for (int i = threadIdx.x; i < EPB; i += 256) atomicAdd(&h[dst[e0 + i] >> 7], 1);
    __syncthreads();
    for (int j = threadIdx.x; j < NBUCK; j += 256) cntmat[blockIdx.x * NBUCK + j] = h[j];
}

// parallel column sums: tot[j] = sum_b cntmat[b][j]
__global__ __launch_bounds__(256) void k_offsA(const int* __restrict__ cntmat, int* __restrict__ tot) {
    int j = blockIdx.x * 256 + threadIdx.x;
    if (j >= NBUCK) return;
    int s = 0;
#pragma unroll 8
    for (int b = 0; b < NBLKA; b++) s += cntmat[b * NBUCK + j];
    tot[j] = s;
}

// single wave: exclusive scan of bucket totals -> bbase
__global__ __launch_bounds__(64) void k_offsB(const int* __restrict__ tot, int* __restrict__ bbase) {
    int tid = threadIdx.x;
    int run = 0;
    for (int c = 0; c < NBUCK; c += 64) {
        int j = c + tid;
        int own = (j < NBUCK) ? tot[j] : 0;
        int v = own;
        for (int off = 1; off < 64; off <<= 1) {
            int u = __shfl_up(v, off);
            if (tid >= off) v += u;
        }
        if (j < NBUCK) bbase[j] = run + v - own;
        run += __shfl(v, 63);
    }
    if (tid == 0) bbase[NBUCK] = NEDGES;
}

// per-(block,bucket) offsets: offmat[b][j] = bbase[j] + prefix_b(cntmat[.][j])
__global__ __launch_bounds__(256) void k_offsC(const int* __restrict__ cntmat, const int* __restrict__ bbase,
                                               int* __restrict__ offmat) {
    int j = blockIdx.x * 256 + threadIdx.x;
    if (j >= NBUCK) return;
    int run = bbase[j];
    for (int b = 0; b < NBLKA; b++) { offmat[b * NBUCK + j] = run; run += cntmat[b * NBUCK + j]; }
}

// place edges into bucket-local regions: LDS cursors, 4B packed record s|dloc<<17
__global__ __launch_bounds__(256) void k_bin(const int* __restrict__ src, const int* __restrict__ dst,
                                             const int* __restrict__ offmat, int* __restrict__ ebin) {
    __shared__ int cur[NBUCK];
    int b = blockIdx.x;
    for (int j = threadIdx.x; j < NBUCK; j += 256) cur[j] = offmat[b * NBUCK + j];
    __syncthreads();
    int e0 = b * EPB;
    for (int i = threadIdx.x; i < EPB; i += 256) {
        int s = src[e0 + i], d = dst[e0 + i];
        int p = atomicAdd(&cur[d >> 7], 1);
        ebin[p] = s | ((d & (NPB - 1)) << 17);
    }
}

// per bucket: histogram + scan -> cnt/rowptr/dinv, then counting-sort src into
// per-node CSR order (cols, 4B). All within the bucket's L2-resident window.
__global__ __launch_bounds__(256) void k_csr(const int* __restrict__ ebin, const int* __restrict__ bbase,
                                             int* __restrict__ cnt, int* __restrict__ rowptr,
                                             float* __restrict__ dinv, int* __restrict__ cols) {
    __shared__ int h[NPB];
    __shared__ int sc[NPB];
    __shared__ int cur[NPB];
    int j = blockIdx.x;
    int tid = threadIdx.x;
    if (tid < NPB) h[tid] = 0;
    __syncthreads();
    int lo = bbase[j], hi = bbase[j + 1];
    for (int i = lo + tid; i < hi; i += 256) atomicAdd(&h[ebin[i] >> 17], 1);
    __syncthreads();
    if (tid < 64) {   // wave 0: exclusive scan over 128 node counts
        int run = 0;
        for (int c = 0; c < NPB; c += 64) {
            int own = h[c + tid];
            int v = own;
            for (int off = 1; off < 64; off <<= 1) {
                int u = __shfl_up(v, off);
                if (tid >= off) v += u;
            }
            sc[c + tid] = run + v - own;
            run += __shfl(v, 63);
        }
    }
    __syncthreads();
    int node = j * NPB + tid;
    if (tid < NPB) {
        cur[tid] = lo + sc[tid];
        if (node < NNODES) {
            int c = h[tid];
            cnt[node] = c;
            rowptr[node] = lo + sc[tid];
            dinv[node] = rsqrtf((float)(c + 1));   // +1 self loop, always > 0
        }
    }
    __syncthreads();
    for (int i = lo + tid; i < hi; i += 256) {
        int r = ebin[i];
        int p = atomicAdd(&cur[r >> 17], 1);
        cols[p] = r & 0x1FFFF;
    }
}

// ---------- transform: t' = (relu?(in)) @ W * dinv, stored fp16 ----------

#define CHK 32
#define CHKP 33   // +1 pad: conflict-free stride

// block = 128 nodes x 2 col-halves (256 threads). Thread owns 32 output cols
// of one node; acc in 32 VGPRs. x staged coalesced to LDS per 32-k chunk.
template <int K, bool RELU>
__global__ __launch_bounds__(256) void k_mm(const float* __restrict__ in, const float* __restrict__ W,
                                            const float* __restrict__ dinv, __half* __restrict__ t_out) {
    __shared__ float xs[128 * CHKP];
    const int tid = threadIdx.x;
    const int lane = tid & 63;
    const int wid = tid >> 6;
    const int jhalf = __builtin_amdgcn_readfirstlane(wid & 1);
    const int nloc = (wid >> 1) * 64 + lane;   // 0..127 local node
    const int node0 = blockIdx.x * 128;
    const int node = node0 + nloc;

    float acc[32];
#pragma unroll
    for (int j = 0; j < 32; j++) acc[j] = 0.f;

    const int c4 = tid & 7;     // float4 slot in row (8 per 32-float chunk)
    const int r0 = tid >> 3;    // 0..31

    for (int ko = 0; ko < K; ko += CHK) {
        __syncthreads();
#pragma unroll
        for (int s = 0; s < 4; s++) {
            int r = r0 + s * 32;
            int gn = node0 + r;
            float4 v = make_float4(0.f, 0.f, 0.f, 0.f);
            if (gn < NNODES) v = *(const float4*)&in[(size_t)gn * K + c4 * 4 + ko];
            if (RELU) {
                v.x = fmaxf(v.x, 0.f); v.y = fmaxf(v.y, 0.f);
                v.z = fmaxf(v.z, 0.f); v.w = fmaxf(v.w, 0.f);
            }
            float* dp = &xs[r * CHKP + c4 * 4];
            dp[0] = v.x; dp[1] = v.y; dp[2] = v.z; dp[3] = v.w;
        }
        __syncthreads();
        for (int kk = 0; kk < CHK; kk++) {
            float xk = xs[nloc * CHKP + kk];
            const float* Wr = &W[(size_t)(ko + kk) * 64 + jhalf * 32];
#pragma unroll
            for (int j = 0; j < 32; j++) acc[j] = fmaf(xk, Wr[j], acc[j]);
        }
    }

    if (node < NNODES) {
        float dv = dinv[node];
        __half* tp = &t_out[(size_t)node * 64 + jhalf * 32];
#pragma unroll
        for (int j4 = 0; j4 < 8; j4++) {
            union { __half2 h[2]; float2 f; } u;
            u.h[0] = __floats2half2_rn(acc[j4*4] * dv, acc[j4*4+1] * dv);
            u.h[1] = __floats2half2_rn(acc[j4*4+2] * dv, acc[j4*4+3] * dv);
            *(float2*)&tp[j4 * 4] = u.f;           // 8B packed fp16 store
        }
    }
}

// ---------- aggregation: B = bias + dinv[d]*(t'[d] + sum_e t'[src]) ----------

__device__ __forceinline__ void agg_edge(const __half* t, int s, int ql, float4& acc) {
    float2 raw = *(const float2*)&t[(size_t)s * 64 + ql * 4];  // 8B = 4 halves
    const __half2* hp = (const __half2*)&raw;
    float2 f0 = __half22float2(hp[0]);
    float2 f1 = __half22float2(hp[1]);
    acc.x += f0.x; acc.y += f0.y; acc.z += f1.x; acc.w += f1.y;
}

__global__ __launch_bounds__(256) void k_agg(const __half* __restrict__ t, const int* __restrict__ rowptr,
                                             const int* __restrict__ cnt, const int* __restrict__ cols,
                                             const float* __restrict__ dinv, const float* __restrict__ bias,
                                             float* __restrict__ B) {
    int w = (blockIdx.x * 256 + threadIdx.x) >> 6;   // node
    int lane = threadIdx.x & 63;
    if (w >= NNODES) return;
    int qg = lane >> 4;      // edge-slot group 0..3
    int ql = lane & 15;      // half4 slot within the 64-half row
    int start = rowptr[w];
    int n = cnt[w];
    float4 acc = make_float4(0.f, 0.f, 0.f, 0.f);
    int e = 0;
    // unrolled: 4 independent cols loads then 4 independent 128B row gathers in flight
    for (; e + 16 <= n; e += 16) {
        int s0 = cols[start + e + qg];
        int s1 = cols[start + e + 4 + qg];
        int s2 = cols[start + e + 8 + qg];
        int s3 = cols[start + e + 12 + qg];
        agg_edge(t, s0, ql, acc);
        agg_edge(t, s1, ql, acc);
        agg_edge(t, s2, ql, acc);
        agg_edge(t, s3, ql, acc);
    }
    for (e += qg; e < n; e += 4) {
        agg_edge(t, cols[start + e], ql, acc);
    }
    // reduce the 4 edge-slot groups (lanes l, l^16, l^32, l^48)
    acc.x += __shfl_xor(acc.x, 16); acc.y += __shfl_xor(acc.y, 16);
    acc.z += __shfl_xor(acc.z, 16); acc.w += __shfl_xor(acc.w, 16);
    acc.x += __shfl_xor(acc.x, 32); acc.y += __shfl_xor(acc.y, 32);
    acc.z += __shfl_xor(acc.z, 32); acc.w += __shfl_xor(acc.w, 32);
    if (qg == 0) {
        // self-loop term: t'[w] (fp16), then scale by dinv[w], add bias
        float2 raw = *(const float2*)&t[(size_t)w * 64 + ql * 4];
        const __half2* hp = (const __half2*)&raw;
        float2 f0 = __half22float2(hp[0]);
        float2 f1 = __half22float2(hp[1]);
        float dv = dinv[w];
        float4 b4 = *(const float4*)&bias[ql * 4];
        float4 o;
        o.x = fmaf(dv, f0.x + acc.x, b4.x);
        o.y = fmaf(dv, f0.y + acc.y, b4.y);
        o.z = fmaf(dv, f1.x + acc.z, b4.z);
        o.w = fmaf(dv, f1.y + acc.w, b4.w);
        *(float4*)&B[(size_t)w * 64 + ql * 4] = o;
    }
}

// ---------- pooling + head ----------

// batch is SORTED: segmented reduction. Wave per 32-node chunk (3125 waves),
// 4-deep unrolled row loads for MLP; flush one atomicAdd per segment boundary.
#define POOL_CHUNK 32
__global__ __launch_bounds__(256) void k_pool(const float* __restrict__ h, const int* __restrict__ batch,
                                              float* pooled, float* gcnt) {
    int w = (blockIdx.x * 256 + threadIdx.x) >> 6;
    int lane = threadIdx.x & 63;
    int start = w * POOL_CHUNK;
    if (start >= NNODES) return;
    int end = min(start + POOL_CHUNK, NNODES);
    int g = batch[start];
    float acc = 0.f;
    float cn = 0.f;
    int i = start;
    for (; i + 4 <= end; i += 4) {
        int b0 = batch[i], b1 = batch[i + 1], b2 = batch[i + 2], b3 = batch[i + 3];
        float v0 = h[(size_t)i * 64 + lane];
        float v1 = h[(size_t)(i + 1) * 64 + lane];
        float v2 = h[(size_t)(i + 2) * 64 + lane];
        float v3 = h[(size_t)(i + 3) * 64 + lane];
        if (b0 != g) {
            atomicAdd(&pooled[g * 64 + lane], acc);
            if (lane == 0) atomicAdd(&gcnt[g], cn);
            g = b0; acc = 0.f; cn = 0.f;
        }
        acc += fmaxf(v0, 0.f); cn += 1.f;
        if (b1 != g) {
            atomicAdd(&pooled[g * 64 + lane], acc);
            if (lane == 0) atomicAdd(&gcnt[g], cn);
            g = b1; acc = 0.f; cn = 0.f;
        }
        acc += fmaxf(v1, 0.f); cn += 1.f;
        if (b2 != g) {
            atomicAdd(&pooled[g * 64 + lane], acc);
            if (lane == 0) atomicAdd(&gcnt[g], cn);
            g = b2; acc = 0.f; cn = 0.f;
        }
        acc += fmaxf(v2, 0.f); cn += 1.f;
        if (b3 != g) {
            atomicAdd(&pooled[g * 64 + lane], acc);
            if (lane == 0) atomicAdd(&gcnt[g], cn);
            g = b3; acc = 0.f; cn = 0.f;
        }
        acc += fmaxf(v3, 0.f); cn += 1.f;
    }
    for (; i < end; i++) {
        int gi = batch[i];
        if (gi != g) {
            atomicAdd(&pooled[g * 64 + lane], acc);
            if (lane == 0) atomicAdd(&gcnt[g], cn);
            g = gi; acc = 0.f; cn = 0.f;
        }
        acc += fmaxf(h[(size_t)i * 64 + lane], 0.f);
        cn += 1.f;
    }
    atomicAdd(&pooled[g * 64 + lane], acc);
    if (lane == 0) atomicAdd(&gcnt[g], cn);
}

__global__ __launch_bounds__(256) void k_final(const float* __restrict__ pooled, const float* __restrict__ gcnt,
                                               const float* __restrict__ Wl, const float* __restrict__ bl,
                                               float* __restrict__ out) {
    int g = (blockIdx.x * 256 + threadIdx.x) >> 6;
    int lane = threadIdx.x & 63;
    if (g >= NGRAPHS) return;
    float c = fmaxf(gcnt[g], 1.f);
    float v = pooled[g * 64 + lane] / c * Wl[lane];
#pragma unroll
    for (int off = 32; off; off >>= 1) v += __shfl_down(v, off);
    if (lane == 0) out[g] = v + bl[0];
}

// ---------- launch ----------

extern "C" void kernel_launch(void* const* d_in, const int* in_sizes, int n_in,
                              void* d_out, int out_size, void* d_ws, size_t ws_size,
                              hipStream_t stream) {
    const float* x  = (const float*)d_in[0];
    const int* ei   = (const int*)d_in[1];
    const int* batch = (const int*)d_in[2];
    const float* W1 = (const float*)d_in[3];
    const float* b1 = (const float*)d_in[4];
    const float* W2 = (const float*)d_in[5];
    const float* b2 = (const float*)d_in[6];
    const float* W3 = (const float*)d_in[7];
    const float* b3 = (const float*)d_in[8];
    const float* Wl = (const float*)d_in[9];
    const float* bl = (const float*)d_in[10];
    const int* src = ei;
    const int* dst = ei + NEDGES;

    char* ws = (char*)d_ws;
    size_t off = 0;
    auto alloc = [&](size_t bytes) { void* p = ws + off; off += (bytes + 255) & ~size_t(255); return p; };
    __half* A      = (__half*)alloc((size_t)NNODES * 64 * 2);   // fp16 t' buffer (12.8MB)
    float*  B      = (float*)alloc((size_t)NNODES * 64 * 4);
    int*    cols   = (int*)alloc((size_t)NEDGES * 4);           // CSR src indices (12.8MB)
    float*  dinv   = (float*)alloc((size_t)NNODES * 4);
    int*    cnt    = (int*)alloc((size_t)NNODES * 4);
    int*    rowptr = (int*)alloc((size_t)NNODES * 4);
    int*    cntmat = (int*)alloc((size_t)NBLKA * NBUCK * 4);
    int*    offmat = (int*)alloc((size_t)NBLKA * NBUCK * 4);
    int*    tot    = (int*)alloc(NBUCK * 4);
    int*    bbase  = (int*)alloc((NBUCK + 1) * 4);
    float*  pooled = (float*)alloc(NGRAPHS * 64 * 4);
    float*  gcnt   = (float*)alloc(NGRAPHS * 4);
    float*  out    = (float*)d_out;
    int*    ebin   = (int*)A;   // 12.8MB staging aliases A (dead before layer-1 k_mm writes A)

    const int NB_MM = (NNODES + 127) / 128;
    const int NB_W  = ((size_t)NNODES * 64 + 255) / 256;
    const int NB_PL = ((NNODES + POOL_CHUNK - 1) / POOL_CHUNK + 3) / 4;
    const int NB_J  = (NBUCK + 255) / 256;

    k_init<<<(NGRAPHS * HID + 255) / 256, 256, 0, stream>>>(pooled, gcnt);
    k_hist<<<NBLKA, 256, 0, stream>>>(dst, cntmat);
    k_offsA<<<NB_J, 256, 0, stream>>>(cntmat, tot);
    k_offsB<<<1, 64, 0, stream>>>(tot, bbase);
    k_offsC<<<NB_J, 256, 0, stream>>>(cntmat, bbase, offmat);
    k_bin<<<NBLKA, 256, 0, stream>>>(src, dst, offmat, ebin);
    k_csr<<<NBUCK, 256, 0, stream>>>(ebin, bbase, cnt, rowptr, dinv, cols);

    // layer 1: x[N,128] -> A = t' (fp16); B = bias + dinv*(t'[self] + sum t'[src])
    k_mm<128, false><<<NB_MM, 256, 0, stream>>>(x, W1, dinv, A);
    k_agg<<<NB_W, 256, 0, stream>>>(A, rowptr, cnt, cols, dinv, b1, B);
    // layer 2 (relu on read)
    k_mm<64, true><<<NB_MM, 256, 0, stream>>>(B, W2, dinv, A);
    k_agg<<<NB_W, 256, 0, stream>>>(A, rowptr, cnt, cols, dinv, b2, B);
    // layer 3
    k_mm<64, true><<<NB_MM, 256, 0, stream>>>(B, W3, dinv, A);
    k_agg<<<NB_W, 256, 0, stream>>>(A, rowptr, cnt, cols, dinv, b3, B);

    k_pool<<<NB_PL, 256, 0, stream>>>(B, batch, pooled, gcnt);
    k_final<<<(NGRAPHS * 64 + 255) / 256, 256, 0, stream>>>(pooled, gcnt, Wl, bl, out);
}